// Round 2
// baseline (42979.596 us; speedup 1.0000x reference)
//
#include <hip/hip_runtime.h>
#include <math.h>

#define Bn 64
#define Sn 512
#define Dn 256
#define Hn 512
#define G4n 2048
#define On 128

__device__ __forceinline__ float sigmoidf(float x) { return 1.0f / (1.0f + expf(-x)); }

__global__ __launch_bounds__(256) void bias_prep(const float* __restrict__ bi_f, const float* __restrict__ bh_f,
                                                 const float* __restrict__ bi_b, const float* __restrict__ bh_b,
                                                 float* __restrict__ out) {
    int i = blockIdx.x * 256 + threadIdx.x;
    if (i < G4n) {
        out[i] = bi_f[i] + bh_f[i];
        out[G4n + i] = bi_b[i] + bh_b[i];
    }
}

__global__ __launch_bounds__(256) void zero_kernel(float* __restrict__ p, int n) {
    int i = blockIdx.x * 256 + threadIdx.x;
    if (i < n) p[i] = 0.0f;
}

// One LSTM time step (one direction handled per blockIdx.z slice).
// Fused GEMM: gates[16b x 64g] = [x_t | h_prev] @ [w_ih | w_hh]^T  (K = Din + H)
// Block tile: 16 batches x (4 gates x 16 hidden). 256 threads, 2x2 micro-tile.
// Then LSTM cell update for this block's 16 hidden units x 16 batches.
__global__ __launch_bounds__(256) void lstm_step(
    const float* __restrict__ in_seq, int Din,
    const float* __restrict__ w_ih_f, const float* __restrict__ w_ih_b,
    const float* __restrict__ w_hh_f, const float* __restrict__ w_hh_b,
    const float* __restrict__ bias,      // [2][4H] combined b_ih+b_hh
    const float* __restrict__ h_prev,    // [2][B][H]
    float* __restrict__ h_next,          // [2][B][H]
    float* __restrict__ c_state,         // [2][B][H]
    float* __restrict__ out_seq,         // [B][S][2H] or nullptr
    int s, int dir_off)
{
    const int bg  = blockIdx.x;               // 0..3  batch group
    const int hg  = blockIdx.y;               // 0..31 hidden group
    const int dir = blockIdx.z + dir_off;     // 0 fwd, 1 bwd
    const int tid = threadIdx.x;
    const int tt  = (dir == 0) ? s : (Sn - 1 - s);   // actual time index
    const int b0  = bg * 16;
    const int j0  = hg * 16;
    const int K   = Din + Hn;
    const float* __restrict__ w_ih = dir ? w_ih_b : w_ih_f;
    const float* __restrict__ w_hh = dir ? w_hh_b : w_hh_f;

    __shared__ float As[16][36];
    __shared__ float Bs[64][36];
    __shared__ float Gs[64][17];

    const int r2 = (tid >> 5) << 1;   // 0,2,...,14  (batch rows)
    const int c2 = (tid & 31) << 1;   // 0,2,...,62  (gate cols)
    float acc00 = 0.f, acc01 = 0.f, acc10 = 0.f, acc11 = 0.f;

    // fixed per-thread A-load slot: 2 consecutive k per thread
    const int a_idx = tid << 1;
    const int a_row = a_idx >> 5;     // 0..15
    const int a_col = a_idx & 31;
    const size_t in_base = ((size_t)(b0 + a_row) * Sn + tt) * Din;
    const size_t h_base  = ((size_t)dir * Bn + (b0 + a_row)) * Hn;

    for (int k0 = 0; k0 < K; k0 += 32) {
        // stage A: 16x32 activations (x_t for k<Din, h_prev for k>=Din)
        {
            const int k = k0 + a_col;
            float2 v = (k < Din)
                ? *reinterpret_cast<const float2*>(&in_seq[in_base + k])
                : *reinterpret_cast<const float2*>(&h_prev[h_base + (k - Din)]);
            As[a_row][a_col]     = v.x;
            As[a_row][a_col + 1] = v.y;
        }
        // stage B: 64x32 weight rows; block col c -> weight row (c>>4)*H + j0 + (c&15)
        #pragma unroll
        for (int li = 0; li < 2; ++li) {
            const int idx = (tid + li * 256) << 2;
            const int row = idx >> 5;     // 0..63
            const int col = idx & 31;     // multiple of 4
            const int wrow = (row >> 4) * Hn + j0 + (row & 15);
            const int k = k0 + col;
            float4 v = (k < Din)
                ? *reinterpret_cast<const float4*>(&w_ih[(size_t)wrow * Din + k])
                : *reinterpret_cast<const float4*>(&w_hh[(size_t)wrow * Hn + (k - Din)]);
            *reinterpret_cast<float4*>(&Bs[row][col]) = v;
        }
        __syncthreads();
        #pragma unroll
        for (int kk = 0; kk < 32; kk += 4) {
            const float4 a0  = *reinterpret_cast<const float4*>(&As[r2][kk]);
            const float4 a1  = *reinterpret_cast<const float4*>(&As[r2 + 1][kk]);
            const float4 bv0 = *reinterpret_cast<const float4*>(&Bs[c2][kk]);
            const float4 bv1 = *reinterpret_cast<const float4*>(&Bs[c2 + 1][kk]);
            acc00 += a0.x * bv0.x + a0.y * bv0.y + a0.z * bv0.z + a0.w * bv0.w;
            acc01 += a0.x * bv1.x + a0.y * bv1.y + a0.z * bv1.z + a0.w * bv1.w;
            acc10 += a1.x * bv0.x + a1.y * bv0.y + a1.z * bv0.z + a1.w * bv0.w;
            acc11 += a1.x * bv1.x + a1.y * bv1.y + a1.z * bv1.z + a1.w * bv1.w;
        }
        __syncthreads();
    }

    // remap gates through LDS so one thread owns all 4 gates of one (b, j)
    Gs[c2][r2]         = acc00;
    Gs[c2 + 1][r2]     = acc01;
    Gs[c2][r2 + 1]     = acc10;
    Gs[c2 + 1][r2 + 1] = acc11;
    __syncthreads();

    const int bb = tid >> 4;   // 0..15 batch
    const int jj = tid & 15;   // 0..15 hidden
    const float vi = Gs[0 * 16 + jj][bb] + bias[dir * G4n + 0 * Hn + j0 + jj];
    const float vf = Gs[1 * 16 + jj][bb] + bias[dir * G4n + 1 * Hn + j0 + jj];
    const float vg = Gs[2 * 16 + jj][bb] + bias[dir * G4n + 2 * Hn + j0 + jj];
    const float vo = Gs[3 * 16 + jj][bb] + bias[dir * G4n + 3 * Hn + j0 + jj];
    const float ig = sigmoidf(vi);
    const float fg = sigmoidf(vf);
    const float gg = tanhf(vg);
    const float og = sigmoidf(vo);
    const size_t cidx = ((size_t)dir * Bn + (b0 + bb)) * Hn + (j0 + jj);
    const float c = fg * c_state[cidx] + ig * gg;
    c_state[cidx] = c;
    const float h = og * tanhf(c);
    h_next[cidx] = h;
    if (out_seq) {
        out_seq[((size_t)(b0 + bb) * Sn + tt) * (2 * Hn) + dir * Hn + (j0 + jj)] = h;
    }
}

// out[b][o] = fc_b[o] + sum_j last[b][j] * fc_w[o][j], last = [hf_final | hb_first]
__global__ __launch_bounds__(128) void fc_kernel(
    const float* __restrict__ hf, const float* __restrict__ hb,
    const float* __restrict__ fc_w, const float* __restrict__ fc_b,
    float* __restrict__ out)
{
    const int b = blockIdx.x;
    const int o = threadIdx.x;
    const float* __restrict__ w = &fc_w[(size_t)o * (2 * Hn)];
    const float* __restrict__ hfb = &hf[(size_t)b * Hn];
    const float* __restrict__ hbb = &hb[(size_t)b * Hn];
    float sum = fc_b[o];
    for (int j = 0; j < Hn; ++j) sum += hfb[j] * w[j];
    for (int j = 0; j < Hn; ++j) sum += hbb[j] * w[Hn + j];
    out[(size_t)b * On + o] = sum;
}

extern "C" void kernel_launch(void* const* d_in, const int* in_sizes, int n_in,
                              void* d_out, int out_size, void* d_ws, size_t ws_size,
                              hipStream_t stream)
{
    const float* x         = (const float*)d_in[0];
    const float* w_ih_l0_f = (const float*)d_in[1];
    const float* w_hh_l0_f = (const float*)d_in[2];
    const float* b_ih_l0_f = (const float*)d_in[3];
    const float* b_hh_l0_f = (const float*)d_in[4];
    const float* w_ih_l0_b = (const float*)d_in[5];
    const float* w_hh_l0_b = (const float*)d_in[6];
    const float* b_ih_l0_b = (const float*)d_in[7];
    const float* b_hh_l0_b = (const float*)d_in[8];
    const float* w_ih_l1_f = (const float*)d_in[9];
    const float* w_hh_l1_f = (const float*)d_in[10];
    const float* b_ih_l1_f = (const float*)d_in[11];
    const float* b_hh_l1_f = (const float*)d_in[12];
    const float* w_ih_l1_b = (const float*)d_in[13];
    const float* w_hh_l1_b = (const float*)d_in[14];
    const float* b_ih_l1_b = (const float*)d_in[15];
    const float* b_hh_l1_b = (const float*)d_in[16];
    const float* fc_w      = (const float*)d_in[17];
    const float* fc_b      = (const float*)d_in[18];

    float* ws    = (float*)d_ws;
    float* out0  = ws;                                   // B*S*2H = 33,554,432 f
    float* hbuf  = out0 + (size_t)Bn * Sn * 2 * Hn;      // [parity][dir][B][H] = 131072 f
    float* cbuf  = hbuf + 2 * 2 * Bn * Hn;               // [dir][B][H] = 65536 f
    float* bias0 = cbuf + 2 * Bn * Hn;                   // [2][4H]
    float* bias1 = bias0 + 2 * G4n;                      // [2][4H]

    hipLaunchKernelGGL(bias_prep, dim3(8), dim3(256), 0, stream,
                       b_ih_l0_f, b_hh_l0_f, b_ih_l0_b, b_hh_l0_b, bias0);
    hipLaunchKernelGGL(bias_prep, dim3(8), dim3(256), 0, stream,
                       b_ih_l1_f, b_hh_l1_f, b_ih_l1_b, b_hh_l1_b, bias1);

    const int state_n = 2 * 2 * Bn * Hn + 2 * Bn * Hn;   // hbuf + cbuf (contiguous)

    // ---- layer 0, both directions, full sequence into out0 ----
    hipLaunchKernelGGL(zero_kernel, dim3((state_n + 255) / 256), dim3(256), 0, stream, hbuf, state_n);
    for (int s = 0; s < Sn; ++s) {
        float* hp = hbuf + (size_t)(s & 1) * 2 * Bn * Hn;
        float* hn = hbuf + (size_t)((s + 1) & 1) * 2 * Bn * Hn;
        hipLaunchKernelGGL(lstm_step, dim3(4, 32, 2), dim3(256), 0, stream,
            x, Dn, w_ih_l0_f, w_ih_l0_b, w_hh_l0_f, w_hh_l0_b, bias0,
            hp, hn, cbuf, out0, s, 0);
    }

    // ---- layer 1 forward (only final h needed; no sequence store) ----
    hipLaunchKernelGGL(zero_kernel, dim3((state_n + 255) / 256), dim3(256), 0, stream, hbuf, state_n);
    for (int s = 0; s < Sn; ++s) {
        float* hp = hbuf + (size_t)(s & 1) * 2 * Bn * Hn;
        float* hn = hbuf + (size_t)((s + 1) & 1) * 2 * Bn * Hn;
        hipLaunchKernelGGL(lstm_step, dim3(4, 32, 1), dim3(256), 0, stream,
            out0, 2 * Hn, w_ih_l1_f, w_ih_l1_b, w_hh_l1_f, w_hh_l1_b, bias1,
            hp, hn, cbuf, nullptr, s, 0);
    }
    // ---- layer 1 backward: only its first scan step (t = S-1) is needed ----
    {
        float* hp = hbuf;                                  // parity 0 (dir1 slots still zero)
        float* hn = hbuf + (size_t)2 * Bn * Hn;            // parity 1
        hipLaunchKernelGGL(lstm_step, dim3(4, 32, 1), dim3(256), 0, stream,
            out0, 2 * Hn, w_ih_l1_f, w_ih_l1_b, w_hh_l1_f, w_hh_l1_b, bias1,
            hp, hn, cbuf, nullptr, 0, 1);
    }

    // ---- FC on [hf_final | hb_first] ----
    const float* hf = hbuf;                                            // parity 0, dir 0 (after 512 steps)
    const float* hb = hbuf + (size_t)2 * Bn * Hn + (size_t)Bn * Hn;    // parity 1, dir 1
    hipLaunchKernelGGL(fc_kernel, dim3(Bn), dim3(On), 0, stream, hf, hb, fc_w, fc_b, (float*)d_out);
}

// Round 3
// 28038.531 us; speedup vs baseline: 1.5329x; 1.5329x over previous
//
#include <hip/hip_runtime.h>
#include <math.h>

#define Bn 64
#define Sn 512
#define Dn 256
#define Hn 512

using short8 = __attribute__((ext_vector_type(8))) short;
using f32x4  = __attribute__((ext_vector_type(4))) float;

__device__ __forceinline__ ushort f2bf(float f) {
    unsigned u = __float_as_uint(f);
    u = u + 0x7FFFu + ((u >> 16) & 1u);   // round-to-nearest-even
    return (ushort)(u >> 16);
}
__device__ __forceinline__ float bf2f(ushort b) {
    return __uint_as_float(((unsigned)b) << 16);
}
// split 8 consecutive fp32 into hi/lo bf16 fragments
__device__ __forceinline__ void split8(const float* __restrict__ p, short8& hi, short8& lo) {
    #pragma unroll
    for (int j = 0; j < 8; ++j) {
        float w = p[j];
        ushort h = f2bf(w);
        hi[j] = (short)h;
        lo[j] = (short)f2bf(w - bf2f(h));
    }
}

// monotonic-count grid barrier; all 256 blocks co-resident (1 block/CU)
__device__ __forceinline__ void gridbar(unsigned* cnt, unsigned target) {
    __syncthreads();
    if (threadIdx.x == 0) {
        __threadfence();  // release: flush this XCD's dirty L2
        __hip_atomic_fetch_add(cnt, 1u, __ATOMIC_RELEASE, __HIP_MEMORY_SCOPE_AGENT);
        while (__hip_atomic_load(cnt, __ATOMIC_RELAXED, __HIP_MEMORY_SCOPE_AGENT) < target)
            __builtin_amdgcn_s_sleep(1);
        __threadfence();  // acquire: invalidate L1/L2 so h reads are fresh
    }
    __syncthreads();
}

__device__ __forceinline__ f32x4 mfma_bf16(short8 a, short8 b, f32x4 c) {
    return __builtin_amdgcn_mfma_f32_16x16x32_bf16(a, b, c, 0, 0, 0);
}

__global__ __launch_bounds__(256, 1) void bilstm_persistent(
    const float* __restrict__ x,
    const float* __restrict__ wih0f, const float* __restrict__ whh0f,
    const float* __restrict__ bih0f, const float* __restrict__ bhh0f,
    const float* __restrict__ wih0b, const float* __restrict__ whh0b,
    const float* __restrict__ bih0b, const float* __restrict__ bhh0b,
    const float* __restrict__ wih1f, const float* __restrict__ whh1f,
    const float* __restrict__ bih1f, const float* __restrict__ bhh1f,
    const float* __restrict__ wih1b, const float* __restrict__ whh1b,
    const float* __restrict__ bih1b, const float* __restrict__ bhh1b,
    const float* __restrict__ fcw,  const float* __restrict__ fcb,
    unsigned* bar,
    ushort* h0_hi, ushort* h0_lo,      // [2 parity][2 dir][B][H]
    ushort* h1_hi, ushort* h1_lo,      // [2 parity][B][H]
    float* h1f32, float* h1b32,        // [B][H]
    ushort* out0_hi, ushort* out0_lo,  // [B][S][2H]
    float* out)
{
    const int bid = blockIdx.x;
    const int tid = threadIdx.x;
    const int l  = tid & 63;    // lane
    const int w  = tid >> 6;    // wave 0..3 (K-split)
    const int lc = l & 15;      // col lane (gate col) / A-row lane (batch)
    const int ks = l >> 4;      // k-segment 0..3 within a 32-k block
    unsigned target = 0;

    __shared__ float P[4 * 4 * 16 * 20];   // [wave][ntile][gatecol][batch+pad]

    //==================== PHASE 1: layer 0, both dirs, 512 steps ====================
    {
        const int dir = bid >> 7;          // 0..127 fwd, 128..255 bwd
        const int hs  = (bid >> 2) & 31;   // hidden slice (16 hidden units)
        const int bt  = bid & 3;           // batch tile (16 batches)
        const float* wih = dir ? wih0b : wih0f;
        const float* whh = dir ? whh0b : whh0f;
        const float* bih = dir ? bih0b : bih0f;
        const float* bhh = dir ? bhh0b : bhh0f;

        // preload weight fragments into VGPRs: B[k][col], col = gate row nt*512+hs*16+lc
        short8 wfh[6][4], wfl[6][4];
        #pragma unroll
        for (int i = 0; i < 6; ++i) {
            const int kg = w * 6 + i;
            const int k0 = kg * 32 + ks * 8;
            #pragma unroll
            for (int nt = 0; nt < 4; ++nt) {
                const int r = nt * 512 + hs * 16 + lc;
                const float* src = (k0 < 256) ? &wih[(size_t)r * 256 + k0]
                                              : &whh[(size_t)r * 512 + (k0 - 256)];
                split8(src, wfh[i][nt], wfl[i][nt]);
            }
        }
        // cell-thread constants: thread t -> (batch, hidden)
        const int cb = bt * 16 + (tid >> 4);
        const int ch = hs * 16 + (tid & 15);
        float bias_r[4];
        #pragma unroll
        for (int gt = 0; gt < 4; ++gt)
            bias_r[gt] = bih[gt * 512 + ch] + bhh[gt * 512 + ch];
        float c_reg = 0.f;
        const int bA = bt * 16 + lc;       // A-operand batch row

        for (int s = 0; s < Sn; ++s) {
            const int p = s & 1;
            const int t = dir ? (Sn - 1 - s) : s;
            f32x4 acc0 = {0.f,0.f,0.f,0.f}, acc1 = acc0, acc2 = acc0, acc3 = acc0;

            #pragma unroll
            for (int i = 0; i < 6; ++i) {
                const int kg = w * 6 + i;
                const int k0 = kg * 32 + ks * 8;
                short8 ah, al;
                if (kg < 8) {               // x part (fp32 -> split on the fly)
                    split8(&x[((size_t)bA * Sn + t) * Dn + k0], ah, al);
                } else {                    // h part (stored as hi/lo bf16)
                    const size_t ho = (((size_t)p * 2 + dir) * Bn + bA) * Hn + (k0 - 256);
                    ah = *(const short8*)&h0_hi[ho];
                    al = *(const short8*)&h0_lo[ho];
                }
                acc0 = mfma_bf16(ah, wfh[i][0], acc0);
                acc0 = mfma_bf16(al, wfh[i][0], acc0);
                acc0 = mfma_bf16(ah, wfl[i][0], acc0);
                acc1 = mfma_bf16(ah, wfh[i][1], acc1);
                acc1 = mfma_bf16(al, wfh[i][1], acc1);
                acc1 = mfma_bf16(ah, wfl[i][1], acc1);
                acc2 = mfma_bf16(ah, wfh[i][2], acc2);
                acc2 = mfma_bf16(al, wfh[i][2], acc2);
                acc2 = mfma_bf16(ah, wfl[i][2], acc2);
                acc3 = mfma_bf16(ah, wfh[i][3], acc3);
                acc3 = mfma_bf16(al, wfh[i][3], acc3);
                acc3 = mfma_bf16(ah, wfl[i][3], acc3);
            }
            // partials -> LDS. C layout: row(batch)=(l>>4)*4+reg, col(gate)=l&15
            {
                float* d0 = &P[((w * 4 + 0) * 16 + lc) * 20 + ks * 4];
                float* d1 = &P[((w * 4 + 1) * 16 + lc) * 20 + ks * 4];
                float* d2 = &P[((w * 4 + 2) * 16 + lc) * 20 + ks * 4];
                float* d3 = &P[((w * 4 + 3) * 16 + lc) * 20 + ks * 4];
                *(f32x4*)d0 = acc0; *(f32x4*)d1 = acc1;
                *(f32x4*)d2 = acc2; *(f32x4*)d3 = acc3;
            }
            __syncthreads();
            // cell update: thread t -> batch (t>>4), hidden (t&15)
            {
                float g4[4];
                #pragma unroll
                for (int gt = 0; gt < 4; ++gt) {
                    float sum = bias_r[gt];
                    #pragma unroll
                    for (int ww = 0; ww < 4; ++ww)
                        sum += P[((ww * 4 + gt) * 16 + (tid & 15)) * 20 + (tid >> 4)];
                    g4[gt] = sum;
                }
                const float ig = 1.f / (1.f + expf(-g4[0]));
                const float fg = 1.f / (1.f + expf(-g4[1]));
                const float gg = tanhf(g4[2]);
                const float og = 1.f / (1.f + expf(-g4[3]));
                c_reg = fg * c_reg + ig * gg;
                const float h = og * tanhf(c_reg);
                const ushort hhv = f2bf(h);
                const ushort hlv = f2bf(h - bf2f(hhv));
                const size_t ho = (((size_t)(p ^ 1) * 2 + dir) * Bn + cb) * Hn + ch;
                __builtin_nontemporal_store(hhv, &h0_hi[ho]);
                __builtin_nontemporal_store(hlv, &h0_lo[ho]);
                const size_t oo = ((size_t)cb * Sn + t) * 1024 + dir * 512 + ch;
                __builtin_nontemporal_store(hhv, &out0_hi[oo]);
                __builtin_nontemporal_store(hlv, &out0_lo[oo]);
            }
            gridbar(bar, target += 256);
        }
    }

    //==================== PHASE 2: layer 1 forward, 512 steps ====================
    {
        const int hs = (bid >> 2) & 63;    // hidden slice (8 hidden units)
        const int bt = bid & 3;
        short8 wfh[12][2], wfl[12][2];
        #pragma unroll
        for (int i = 0; i < 12; ++i) {
            const int kg = w * 12 + i;
            const int k0 = kg * 32 + ks * 8;
            #pragma unroll
            for (int nt = 0; nt < 2; ++nt) {
                const int c = nt * 16 + lc;                 // 0..31
                const int r = (c >> 3) * 512 + hs * 8 + (c & 7);
                const float* src = (k0 < 1024) ? &wih1f[(size_t)r * 1024 + k0]
                                               : &whh1f[(size_t)r * 512 + (k0 - 1024)];
                split8(src, wfh[i][nt], wfl[i][nt]);
            }
        }
        const bool is_cell = (tid < 128);
        const int cb = bt * 16 + (tid >> 3);
        const int ch = hs * 8 + (tid & 7);
        float bias_r[4] = {0.f, 0.f, 0.f, 0.f};
        if (is_cell) {
            #pragma unroll
            for (int gt = 0; gt < 4; ++gt)
                bias_r[gt] = bih1f[gt * 512 + ch] + bhh1f[gt * 512 + ch];
        }
        float c_reg = 0.f;
        const int bA = bt * 16 + lc;

        for (int s = 0; s < Sn; ++s) {
            const int p = s & 1;
            f32x4 acc0 = {0.f,0.f,0.f,0.f}, acc1 = acc0;
            #pragma unroll
            for (int i = 0; i < 12; ++i) {
                const int kg = w * 12 + i;
                const int k0 = kg * 32 + ks * 8;
                short8 ah, al;
                if (kg < 32) {
                    const size_t o = ((size_t)bA * Sn + s) * 1024 + k0;
                    ah = *(const short8*)&out0_hi[o];
                    al = *(const short8*)&out0_lo[o];
                } else {
                    const size_t o = ((size_t)p * Bn + bA) * Hn + (k0 - 1024);
                    ah = *(const short8*)&h1_hi[o];
                    al = *(const short8*)&h1_lo[o];
                }
                acc0 = mfma_bf16(ah, wfh[i][0], acc0);
                acc0 = mfma_bf16(al, wfh[i][0], acc0);
                acc0 = mfma_bf16(ah, wfl[i][0], acc0);
                acc1 = mfma_bf16(ah, wfh[i][1], acc1);
                acc1 = mfma_bf16(al, wfh[i][1], acc1);
                acc1 = mfma_bf16(ah, wfl[i][1], acc1);
            }
            *(f32x4*)&P[((w * 2 + 0) * 16 + lc) * 20 + ks * 4] = acc0;
            *(f32x4*)&P[((w * 2 + 1) * 16 + lc) * 20 + ks * 4] = acc1;
            __syncthreads();
            if (is_cell) {
                float g4[4];
                #pragma unroll
                for (int gt = 0; gt < 4; ++gt) {
                    const int cc = gt * 8 + (tid & 7);
                    const int nt = cc >> 4, g = cc & 15;
                    float sum = bias_r[gt];
                    #pragma unroll
                    for (int ww = 0; ww < 4; ++ww)
                        sum += P[((ww * 2 + nt) * 16 + g) * 20 + (tid >> 3)];
                    g4[gt] = sum;
                }
                const float ig = 1.f / (1.f + expf(-g4[0]));
                const float fg = 1.f / (1.f + expf(-g4[1]));
                const float gg = tanhf(g4[2]);
                const float og = 1.f / (1.f + expf(-g4[3]));
                c_reg = fg * c_reg + ig * gg;
                const float h = og * tanhf(c_reg);
                const ushort hhv = f2bf(h);
                const ushort hlv = f2bf(h - bf2f(hhv));
                const size_t ho = ((size_t)(p ^ 1) * Bn + cb) * Hn + ch;
                __builtin_nontemporal_store(hhv, &h1_hi[ho]);
                __builtin_nontemporal_store(hlv, &h1_lo[ho]);
                __builtin_nontemporal_store(h, &h1f32[(size_t)cb * Hn + ch]);
            }
            gridbar(bar, target += 256);
        }
    }

    //==================== PHASE 3: layer 1 backward, first step only (t = S-1) ====================
    {
        const int hs = (bid >> 2) & 63;
        const int bt = bid & 3;
        const int bA = bt * 16 + lc;
        const int t = Sn - 1;
        f32x4 acc0 = {0.f,0.f,0.f,0.f}, acc1 = acc0;
        #pragma unroll
        for (int i = 0; i < 8; ++i) {          // K = 1024 only (h_prev = 0)
            const int kg = w * 8 + i;
            const int k0 = kg * 32 + ks * 8;
            const size_t o = ((size_t)bA * Sn + t) * 1024 + k0;
            short8 ah = *(const short8*)&out0_hi[o];
            short8 al = *(const short8*)&out0_lo[o];
            #pragma unroll
            for (int nt = 0; nt < 2; ++nt) {
                const int c = nt * 16 + lc;
                const int r = (c >> 3) * 512 + hs * 8 + (c & 7);
                short8 bh, bl;
                split8(&wih1b[(size_t)r * 1024 + k0], bh, bl);
                f32x4 a = (nt == 0) ? acc0 : acc1;
                a = mfma_bf16(ah, bh, a);
                a = mfma_bf16(al, bh, a);
                a = mfma_bf16(ah, bl, a);
                if (nt == 0) acc0 = a; else acc1 = a;
            }
        }
        *(f32x4*)&P[((w * 2 + 0) * 16 + lc) * 20 + ks * 4] = acc0;
        *(f32x4*)&P[((w * 2 + 1) * 16 + lc) * 20 + ks * 4] = acc1;
        __syncthreads();
        if (tid < 128) {
            const int cb = bt * 16 + (tid >> 3);
            const int ch = hs * 8 + (tid & 7);
            float g4[4];
            #pragma unroll
            for (int gt = 0; gt < 4; ++gt) {
                const int cc = gt * 8 + (tid & 7);
                const int nt = cc >> 4, g = cc & 15;
                float sum = bih1b[gt * 512 + ch] + bhh1b[gt * 512 + ch];
                #pragma unroll
                for (int ww = 0; ww < 4; ++ww)
                    sum += P[((ww * 2 + nt) * 16 + g) * 20 + (tid >> 3)];
                g4[gt] = sum;
            }
            const float ig = 1.f / (1.f + expf(-g4[0]));
            const float gg = tanhf(g4[2]);
            const float og = 1.f / (1.f + expf(-g4[3]));
            const float c = ig * gg;           // c_prev = 0
            const float h = og * tanhf(c);
            __builtin_nontemporal_store(h, &h1b32[(size_t)cb * Hn + ch]);
        }
        gridbar(bar, target += 256);
    }

    //==================== PHASE 4: FC ====================
    if (bid < Bn && tid < 128) {
        const int b = bid, o = tid;
        float sum = fcb[o];
        const float* wrow = &fcw[(size_t)o * 1024];
        const float* hf = &h1f32[(size_t)b * Hn];
        const float* hb = &h1b32[(size_t)b * Hn];
        #pragma unroll 4
        for (int j = 0; j < Hn; ++j) sum += hf[j] * wrow[j];
        #pragma unroll 4
        for (int j = 0; j < Hn; ++j) sum += hb[j] * wrow[512 + j];
        out[(size_t)b * 128 + o] = sum;
    }
}

extern "C" void kernel_launch(void* const* d_in, const int* in_sizes, int n_in,
                              void* d_out, int out_size, void* d_ws, size_t ws_size,
                              hipStream_t stream)
{
    const float* x     = (const float*)d_in[0];
    const float* wih0f = (const float*)d_in[1];
    const float* whh0f = (const float*)d_in[2];
    const float* bih0f = (const float*)d_in[3];
    const float* bhh0f = (const float*)d_in[4];
    const float* wih0b = (const float*)d_in[5];
    const float* whh0b = (const float*)d_in[6];
    const float* bih0b = (const float*)d_in[7];
    const float* bhh0b = (const float*)d_in[8];
    const float* wih1f = (const float*)d_in[9];
    const float* whh1f = (const float*)d_in[10];
    const float* bih1f = (const float*)d_in[11];
    const float* bhh1f = (const float*)d_in[12];
    const float* wih1b = (const float*)d_in[13];
    const float* whh1b = (const float*)d_in[14];
    const float* bih1b = (const float*)d_in[15];
    const float* bhh1b = (const float*)d_in[16];
    const float* fcw   = (const float*)d_in[17];
    const float* fcb   = (const float*)d_in[18];

    char* ws = (char*)d_ws;
    size_t off = 0;
    unsigned* bar = (unsigned*)(ws + off); off += 256;
    ushort* h0_hi = (ushort*)(ws + off); off += (size_t)2 * 2 * Bn * Hn * 2;
    ushort* h0_lo = (ushort*)(ws + off); off += (size_t)2 * 2 * Bn * Hn * 2;
    ushort* h1_hi = (ushort*)(ws + off); off += (size_t)2 * Bn * Hn * 2;
    ushort* h1_lo = (ushort*)(ws + off); off += (size_t)2 * Bn * Hn * 2;
    size_t zero_end = off;                    // everything above must start zeroed
    float* h1f32  = (float*)(ws + off);  off += (size_t)Bn * Hn * 4;
    float* h1b32  = (float*)(ws + off);  off += (size_t)Bn * Hn * 4;
    ushort* out0_hi = (ushort*)(ws + off); off += (size_t)Bn * Sn * 2 * Hn * 2;
    ushort* out0_lo = (ushort*)(ws + off); off += (size_t)Bn * Sn * 2 * Hn * 2;

    // zero barrier counter + initial h state (graph-capture-safe async memset)
    hipMemsetAsync(d_ws, 0, zero_end, stream);

    hipLaunchKernelGGL(bilstm_persistent, dim3(256), dim3(256), 0, stream,
        x, wih0f, whh0f, bih0f, bhh0f, wih0b, whh0b, bih0b, bhh0b,
        wih1f, whh1f, bih1f, bhh1f, wih1b, whh1b, bih1b, bhh1b,
        fcw, fcb,
        bar, h0_hi, h0_lo, h1_hi, h1_lo, h1f32, h1b32, out0_hi, out0_lo,
        (float*)d_out);
}

// Round 4
// 20029.550 us; speedup vs baseline: 2.1458x; 1.3999x over previous
//
#include <hip/hip_runtime.h>
#include <math.h>

#define Bn 64
#define Sn 512
#define Dn 256
#define Hn 512

using short8 = __attribute__((ext_vector_type(8))) short;
using f32x4  = __attribute__((ext_vector_type(4))) float;

__device__ __forceinline__ ushort f2bf(float f) {
    unsigned u = __float_as_uint(f);
    u = u + 0x7FFFu + ((u >> 16) & 1u);   // round-to-nearest-even
    return (ushort)(u >> 16);
}
__device__ __forceinline__ float bf2f(ushort b) {
    return __uint_as_float(((unsigned)b) << 16);
}
// split 8 consecutive fp32 into hi/lo bf16 fragments
__device__ __forceinline__ void split8(const float* __restrict__ p, short8& hi, short8& lo) {
    #pragma unroll
    for (int j = 0; j < 8; ++j) {
        float w = p[j];
        ushort h = f2bf(w);
        hi[j] = (short)h;
        lo[j] = (short)f2bf(w - bf2f(h));
    }
}

// ---- decentralized flag sync ----
// publish: all prior stores of this block become agent-visible, then flag := epoch
__device__ __forceinline__ void publish_flag(unsigned* flags, int bid, unsigned epoch) {
    __syncthreads();   // drains this block's vmem stores (compiler emits vmcnt(0))
    if (threadIdx.x == 0) {
        __builtin_amdgcn_fence(__ATOMIC_RELEASE, "agent");   // wbl2: push dirty L2 to LLC
        __hip_atomic_store(&flags[bid], epoch, __ATOMIC_RELAXED, __HIP_MEMORY_SCOPE_AGENT);
    }
}
// wait until flags[base + i*stride] >= epoch for i in 0..n-1 (read-only polling)
__device__ __forceinline__ void wait_flags(unsigned* flags, int base, int stride, int n, unsigned epoch) {
    if ((int)threadIdx.x < n) {
        unsigned* p = &flags[base + (int)threadIdx.x * stride];
        while (__hip_atomic_load(p, __ATOMIC_RELAXED, __HIP_MEMORY_SCOPE_AGENT) < epoch)
            __builtin_amdgcn_s_sleep(1);
    }
    __syncthreads();
    __builtin_amdgcn_fence(__ATOMIC_ACQUIRE, "agent");       // inv L1/L2: see fresh h
}

__device__ __forceinline__ f32x4 mfma_bf16(short8 a, short8 b, f32x4 c) {
    return __builtin_amdgcn_mfma_f32_16x16x32_bf16(a, b, c, 0, 0, 0);
}

__global__ __launch_bounds__(256, 1) void bilstm_persistent(
    const float* __restrict__ x,
    const float* __restrict__ wih0f, const float* __restrict__ whh0f,
    const float* __restrict__ bih0f, const float* __restrict__ bhh0f,
    const float* __restrict__ wih0b, const float* __restrict__ whh0b,
    const float* __restrict__ bih0b, const float* __restrict__ bhh0b,
    const float* __restrict__ wih1f, const float* __restrict__ whh1f,
    const float* __restrict__ bih1f, const float* __restrict__ bhh1f,
    const float* __restrict__ wih1b, const float* __restrict__ whh1b,
    const float* __restrict__ bih1b, const float* __restrict__ bhh1b,
    const float* __restrict__ fcw,  const float* __restrict__ fcb,
    unsigned* flags,
    ushort* h0_hi, ushort* h0_lo,      // [2 parity][2 dir][B][H]
    ushort* h1_hi, ushort* h1_lo,      // [2 parity][B][H]
    float* h1f32, float* h1b32,        // [B][H]
    ushort* out0_hi, ushort* out0_lo,  // [B][S][2H]
    float* out)
{
    const int bid = blockIdx.x;
    const int tid = threadIdx.x;
    const int l  = tid & 63;    // lane
    const int w  = tid >> 6;    // wave 0..3 (K-split)
    const int lc = l & 15;      // col lane (gate col) / A-row lane (batch)
    const int ks = l >> 4;      // k-segment 0..3 within a 32-k block

    __shared__ float P[4 * 4 * 16 * 20];   // [wave][ntile][gatecol][batch+pad]

    //==================== PHASE 1: layer 0, both dirs, 512 steps ====================
    {
        const int dir = bid >> 7;          // 0..127 fwd, 128..255 bwd
        const int hs  = (bid >> 2) & 31;   // hidden slice (16 hidden units)
        const int bt  = bid & 3;           // batch tile (16 batches)
        const float* wih = dir ? wih0b : wih0f;
        const float* whh = dir ? whh0b : whh0f;
        const float* bih = dir ? bih0b : bih0f;
        const float* bhh = dir ? bhh0b : bhh0f;

        // preload weight fragments into VGPRs: B[k][col], col = gate row nt*512+hs*16+lc
        short8 wfh[6][4], wfl[6][4];
        #pragma unroll
        for (int i = 0; i < 6; ++i) {
            const int kg = w * 6 + i;
            const int k0 = kg * 32 + ks * 8;
            #pragma unroll
            for (int nt = 0; nt < 4; ++nt) {
                const int r = nt * 512 + hs * 16 + lc;
                const float* src = (k0 < 256) ? &wih[(size_t)r * 256 + k0]
                                              : &whh[(size_t)r * 512 + (k0 - 256)];
                split8(src, wfh[i][nt], wfl[i][nt]);
            }
        }
        // cell-thread constants: thread t -> (batch, hidden)
        const int cb = bt * 16 + (tid >> 4);
        const int ch = hs * 16 + (tid & 15);
        float bias_r[4];
        #pragma unroll
        for (int gt = 0; gt < 4; ++gt)
            bias_r[gt] = bih[gt * 512 + ch] + bhh[gt * 512 + ch];
        float c_reg = 0.f;
        const int bA = bt * 16 + lc;       // A-operand batch row

        for (int s = 0; s < Sn; ++s) {
            // sync group: same (dir, bt), 32 blocks, flag indices dir*128 + bt + 4*hs
            wait_flags(flags, dir * 128 + bt, 4, 32, (unsigned)s);

            const int p = s & 1;
            const int t = dir ? (Sn - 1 - s) : s;
            f32x4 acc0 = {0.f,0.f,0.f,0.f}, acc1 = acc0, acc2 = acc0, acc3 = acc0;

            #pragma unroll
            for (int i = 0; i < 6; ++i) {
                const int kg = w * 6 + i;
                const int k0 = kg * 32 + ks * 8;
                short8 ah, al;
                if (kg < 8) {               // x part (fp32 -> split on the fly)
                    split8(&x[((size_t)bA * Sn + t) * Dn + k0], ah, al);
                } else {                    // h part (stored as hi/lo bf16)
                    const size_t ho = (((size_t)p * 2 + dir) * Bn + bA) * Hn + (k0 - 256);
                    ah = *(const short8*)&h0_hi[ho];
                    al = *(const short8*)&h0_lo[ho];
                }
                acc0 = mfma_bf16(ah, wfh[i][0], acc0);
                acc0 = mfma_bf16(al, wfh[i][0], acc0);
                acc0 = mfma_bf16(ah, wfl[i][0], acc0);
                acc1 = mfma_bf16(ah, wfh[i][1], acc1);
                acc1 = mfma_bf16(al, wfh[i][1], acc1);
                acc1 = mfma_bf16(ah, wfl[i][1], acc1);
                acc2 = mfma_bf16(ah, wfh[i][2], acc2);
                acc2 = mfma_bf16(al, wfh[i][2], acc2);
                acc2 = mfma_bf16(ah, wfl[i][2], acc2);
                acc3 = mfma_bf16(ah, wfh[i][3], acc3);
                acc3 = mfma_bf16(al, wfh[i][3], acc3);
                acc3 = mfma_bf16(ah, wfl[i][3], acc3);
            }
            // partials -> LDS. C layout: row(batch)=(l>>4)*4+reg, col(gate)=l&15
            {
                float* d0 = &P[((w * 4 + 0) * 16 + lc) * 20 + ks * 4];
                float* d1 = &P[((w * 4 + 1) * 16 + lc) * 20 + ks * 4];
                float* d2 = &P[((w * 4 + 2) * 16 + lc) * 20 + ks * 4];
                float* d3 = &P[((w * 4 + 3) * 16 + lc) * 20 + ks * 4];
                *(f32x4*)d0 = acc0; *(f32x4*)d1 = acc1;
                *(f32x4*)d2 = acc2; *(f32x4*)d3 = acc3;
            }
            __syncthreads();
            // cell update: thread t -> batch (t>>4), hidden (t&15)
            {
                float g4[4];
                #pragma unroll
                for (int gt = 0; gt < 4; ++gt) {
                    float sum = bias_r[gt];
                    #pragma unroll
                    for (int ww = 0; ww < 4; ++ww)
                        sum += P[((ww * 4 + gt) * 16 + (tid & 15)) * 20 + (tid >> 4)];
                    g4[gt] = sum;
                }
                const float ig = 1.f / (1.f + expf(-g4[0]));
                const float fg = 1.f / (1.f + expf(-g4[1]));
                const float gg = tanhf(g4[2]);
                const float og = 1.f / (1.f + expf(-g4[3]));
                c_reg = fg * c_reg + ig * gg;
                const float h = og * tanhf(c_reg);
                const ushort hhv = f2bf(h);
                const ushort hlv = f2bf(h - bf2f(hhv));
                const size_t ho = (((size_t)(p ^ 1) * 2 + dir) * Bn + cb) * Hn + ch;
                h0_hi[ho] = hhv;                       // normal stores: flushed by release
                h0_lo[ho] = hlv;
                const size_t oo = ((size_t)cb * Sn + t) * 1024 + dir * 512 + ch;
                __builtin_nontemporal_store(hhv, &out0_hi[oo]);
                __builtin_nontemporal_store(hlv, &out0_lo[oo]);
            }
            publish_flag(flags, bid, (unsigned)(s + 1));
        }
    }

    //==================== PHASE 2: layer 1 forward, 512 steps ====================
    {
        const int hs = (bid >> 2) & 63;    // hidden slice (8 hidden units)
        const int bt = bid & 3;
        short8 wfh[12][2], wfl[12][2];
        #pragma unroll
        for (int i = 0; i < 12; ++i) {
            const int kg = w * 12 + i;
            const int k0 = kg * 32 + ks * 8;
            #pragma unroll
            for (int nt = 0; nt < 2; ++nt) {
                const int c = nt * 16 + lc;                 // 0..31
                const int r = (c >> 3) * 512 + hs * 8 + (c & 7);
                const float* src = (k0 < 1024) ? &wih1f[(size_t)r * 1024 + k0]
                                               : &whh1f[(size_t)r * 512 + (k0 - 1024)];
                split8(src, wfh[i][nt], wfl[i][nt]);
            }
        }
        const bool is_cell = (tid < 128);
        const int cb = bt * 16 + (tid >> 3);
        const int ch = hs * 8 + (tid & 7);
        float bias_r[4] = {0.f, 0.f, 0.f, 0.f};
        if (is_cell) {
            #pragma unroll
            for (int gt = 0; gt < 4; ++gt)
                bias_r[gt] = bih1f[gt * 512 + ch] + bhh1f[gt * 512 + ch];
        }
        float c_reg = 0.f;
        const int bA = bt * 16 + lc;

        for (int s = 0; s < Sn; ++s) {
            // sync group: same bt, 64 blocks (covers both phase-1 producer groups)
            wait_flags(flags, bt, 4, 64, (unsigned)(Sn + s));

            const int p = s & 1;
            f32x4 acc0 = {0.f,0.f,0.f,0.f}, acc1 = acc0;
            #pragma unroll
            for (int i = 0; i < 12; ++i) {
                const int kg = w * 12 + i;
                const int k0 = kg * 32 + ks * 8;
                short8 ah, al;
                if (kg < 32) {
                    const size_t o = ((size_t)bA * Sn + s) * 1024 + k0;
                    ah = *(const short8*)&out0_hi[o];
                    al = *(const short8*)&out0_lo[o];
                } else {
                    const size_t o = ((size_t)p * Bn + bA) * Hn + (k0 - 1024);
                    ah = *(const short8*)&h1_hi[o];
                    al = *(const short8*)&h1_lo[o];
                }
                acc0 = mfma_bf16(ah, wfh[i][0], acc0);
                acc0 = mfma_bf16(al, wfh[i][0], acc0);
                acc0 = mfma_bf16(ah, wfl[i][0], acc0);
                acc1 = mfma_bf16(ah, wfh[i][1], acc1);
                acc1 = mfma_bf16(al, wfh[i][1], acc1);
                acc1 = mfma_bf16(ah, wfl[i][1], acc1);
            }
            *(f32x4*)&P[((w * 2 + 0) * 16 + lc) * 20 + ks * 4] = acc0;
            *(f32x4*)&P[((w * 2 + 1) * 16 + lc) * 20 + ks * 4] = acc1;
            __syncthreads();
            if (is_cell) {
                float g4[4];
                #pragma unroll
                for (int gt = 0; gt < 4; ++gt) {
                    const int cc = gt * 8 + (tid & 7);
                    const int nt = cc >> 4, g = cc & 15;
                    float sum = bias_r[gt];
                    #pragma unroll
                    for (int ww = 0; ww < 4; ++ww)
                        sum += P[((ww * 2 + nt) * 16 + g) * 20 + (tid >> 3)];
                    g4[gt] = sum;
                }
                const float ig = 1.f / (1.f + expf(-g4[0]));
                const float fg = 1.f / (1.f + expf(-g4[1]));
                const float gg = tanhf(g4[2]);
                const float og = 1.f / (1.f + expf(-g4[3]));
                c_reg = fg * c_reg + ig * gg;
                const float h = og * tanhf(c_reg);
                const ushort hhv = f2bf(h);
                const ushort hlv = f2bf(h - bf2f(hhv));
                const size_t ho = ((size_t)(p ^ 1) * Bn + cb) * Hn + ch;
                h1_hi[ho] = hhv;
                h1_lo[ho] = hlv;
                if (s == Sn - 1)
                    h1f32[(size_t)cb * Hn + ch] = h;
            }
            publish_flag(flags, bid, (unsigned)(Sn + s + 1));
        }
    }

    //==================== PHASE 3: layer 1 backward, first step only (t = S-1) ====================
    {
        const int hs = (bid >> 2) & 63;
        const int bt = bid & 3;
        const int bA = bt * 16 + lc;
        const int t = Sn - 1;
        // needs only out0[:, S-1, :]: dir0 slice published at epoch 512, dir1 slice at
        // epoch 1 — both already guaranteed by this block's phase-2 waits. No new wait.
        f32x4 acc0 = {0.f,0.f,0.f,0.f}, acc1 = acc0;
        #pragma unroll
        for (int i = 0; i < 8; ++i) {          // K = 1024 only (h_prev = 0)
            const int kg = w * 8 + i;
            const int k0 = kg * 32 + ks * 8;
            const size_t o = ((size_t)bA * Sn + t) * 1024 + k0;
            short8 ah = *(const short8*)&out0_hi[o];
            short8 al = *(const short8*)&out0_lo[o];
            #pragma unroll
            for (int nt = 0; nt < 2; ++nt) {
                const int c = nt * 16 + lc;
                const int r = (c >> 3) * 512 + hs * 8 + (c & 7);
                short8 bh, bl;
                split8(&wih1b[(size_t)r * 1024 + k0], bh, bl);
                f32x4 a = (nt == 0) ? acc0 : acc1;
                a = mfma_bf16(ah, bh, a);
                a = mfma_bf16(al, bh, a);
                a = mfma_bf16(ah, bl, a);
                if (nt == 0) acc0 = a; else acc1 = a;
            }
        }
        *(f32x4*)&P[((w * 2 + 0) * 16 + lc) * 20 + ks * 4] = acc0;
        *(f32x4*)&P[((w * 2 + 1) * 16 + lc) * 20 + ks * 4] = acc1;
        __syncthreads();
        if (tid < 128) {
            const int cb = bt * 16 + (tid >> 3);
            const int ch = hs * 8 + (tid & 7);
            float g4[4];
            #pragma unroll
            for (int gt = 0; gt < 4; ++gt) {
                const int cc = gt * 8 + (tid & 7);
                const int nt = cc >> 4, g = cc & 15;
                float sum = bih1b[gt * 512 + ch] + bhh1b[gt * 512 + ch];
                #pragma unroll
                for (int ww = 0; ww < 4; ++ww)
                    sum += P[((ww * 2 + nt) * 16 + g) * 20 + (tid >> 3)];
                g4[gt] = sum;
            }
            const float ig = 1.f / (1.f + expf(-g4[0]));
            const float gg = tanhf(g4[2]);
            const float og = 1.f / (1.f + expf(-g4[3]));
            const float c = ig * gg;           // c_prev = 0
            const float h = og * tanhf(c);
            h1b32[(size_t)cb * Hn + ch] = h;
        }
        publish_flag(flags, bid, (unsigned)(2 * Sn + 1));
    }

    //==================== PHASE 4: FC (after global wait) ====================
    wait_flags(flags, 0, 1, 256, (unsigned)(2 * Sn + 1));
    if (bid < Bn && tid < 128) {
        const int b = bid, o = tid;
        float sum = fcb[o];
        const float* wrow = &fcw[(size_t)o * 1024];
        const float* hf = &h1f32[(size_t)b * Hn];
        const float* hb = &h1b32[(size_t)b * Hn];
        #pragma unroll 4
        for (int j = 0; j < Hn; ++j) sum += hf[j] * wrow[j];
        #pragma unroll 4
        for (int j = 0; j < Hn; ++j) sum += hb[j] * wrow[512 + j];
        out[(size_t)b * 128 + o] = sum;
    }
}

extern "C" void kernel_launch(void* const* d_in, const int* in_sizes, int n_in,
                              void* d_out, int out_size, void* d_ws, size_t ws_size,
                              hipStream_t stream)
{
    const float* x     = (const float*)d_in[0];
    const float* wih0f = (const float*)d_in[1];
    const float* whh0f = (const float*)d_in[2];
    const float* bih0f = (const float*)d_in[3];
    const float* bhh0f = (const float*)d_in[4];
    const float* wih0b = (const float*)d_in[5];
    const float* whh0b = (const float*)d_in[6];
    const float* bih0b = (const float*)d_in[7];
    const float* bhh0b = (const float*)d_in[8];
    const float* wih1f = (const float*)d_in[9];
    const float* whh1f = (const float*)d_in[10];
    const float* bih1f = (const float*)d_in[11];
    const float* bhh1f = (const float*)d_in[12];
    const float* wih1b = (const float*)d_in[13];
    const float* whh1b = (const float*)d_in[14];
    const float* bih1b = (const float*)d_in[15];
    const float* bhh1b = (const float*)d_in[16];
    const float* fcw   = (const float*)d_in[17];
    const float* fcb   = (const float*)d_in[18];

    char* ws = (char*)d_ws;
    size_t off = 0;
    unsigned* flags = (unsigned*)(ws + off); off += 256 * sizeof(unsigned);
    ushort* h0_hi = (ushort*)(ws + off); off += (size_t)2 * 2 * Bn * Hn * 2;
    ushort* h0_lo = (ushort*)(ws + off); off += (size_t)2 * 2 * Bn * Hn * 2;
    ushort* h1_hi = (ushort*)(ws + off); off += (size_t)2 * Bn * Hn * 2;
    ushort* h1_lo = (ushort*)(ws + off); off += (size_t)2 * Bn * Hn * 2;
    size_t zero_end = off;                    // flags + all h state must start zeroed
    float* h1f32  = (float*)(ws + off);  off += (size_t)Bn * Hn * 4;
    float* h1b32  = (float*)(ws + off);  off += (size_t)Bn * Hn * 4;
    ushort* out0_hi = (ushort*)(ws + off); off += (size_t)Bn * Sn * 2 * Hn * 2;
    ushort* out0_lo = (ushort*)(ws + off); off += (size_t)Bn * Sn * 2 * Hn * 2;

    // zero flags + initial h state (graph-capture-safe async memset, runs every replay)
    hipMemsetAsync(d_ws, 0, zero_end, stream);

    hipLaunchKernelGGL(bilstm_persistent, dim3(256), dim3(256), 0, stream,
        x, wih0f, whh0f, bih0f, bhh0f, wih0b, whh0b, bih0b, bhh0b,
        wih1f, whh1f, bih1f, bhh1f, wih1b, whh1b, bih1b, bhh1b,
        fcw, fcb,
        flags, h0_hi, h0_lo, h1_hi, h1_lo, h1f32, h1b32, out0_hi, out0_lo,
        (float*)d_out);
}

// Round 6
// 8163.566 us; speedup vs baseline: 5.2648x; 2.4535x over previous
//
#include <hip/hip_runtime.h>
#include <math.h>

#define Bn 64
#define Sn 512
#define Dn 256
#define Hn 512
#define On 128
#define FLAG_PAD 32   // one 128B cacheline per flag

using short8 = __attribute__((ext_vector_type(8))) short;
using f32x4  = __attribute__((ext_vector_type(4))) float;

union U8 { unsigned u[4]; short8 s; };

__device__ __forceinline__ ushort f2bf(float f) {
    unsigned u = __float_as_uint(f);
    u = u + 0x7FFFu + ((u >> 16) & 1u);   // round-to-nearest-even
    return (ushort)(u >> 16);
}
__device__ __forceinline__ float bf2f(ushort b) {
    return __uint_as_float(((unsigned)b) << 16);
}
// split 8 consecutive fp32 into hi/lo bf16 fragments
__device__ __forceinline__ void split8(const float* __restrict__ p, short8& hi, short8& lo) {
    #pragma unroll
    for (int j = 0; j < 8; ++j) {
        float w = p[j];
        ushort h = f2bf(w);
        hi[j] = (short)h;
        lo[j] = (short)f2bf(w - bf2f(h));
    }
}

// ---- LLC-coherent data access via relaxed agent atomics (proven primitive) ----
// load 8 packed u32 words (hi|lo<<16) as 4x 8B atomic loads
__device__ __forceinline__ void lda8(const unsigned* p, unsigned* w) {
    const unsigned long long* q = (const unsigned long long*)p;
    #pragma unroll
    for (int j = 0; j < 4; ++j) {
        unsigned long long v = __hip_atomic_load(q + j, __ATOMIC_RELAXED, __HIP_MEMORY_SCOPE_AGENT);
        w[2*j]   = (unsigned)v;
        w[2*j+1] = (unsigned)(v >> 32);
    }
}
__device__ __forceinline__ void unpack8(const unsigned* w, short8& hi8, short8& lo8) {
    U8 a, b;
    #pragma unroll
    for (int j = 0; j < 4; ++j) {
        a.u[j] = (w[2*j] & 0xffffu) | (w[2*j+1] << 16);
        b.u[j] = (w[2*j] >> 16)     | (w[2*j+1] & 0xffff0000u);
    }
    hi8 = a.s; lo8 = b.s;
}
__device__ __forceinline__ void sta32(unsigned* p, unsigned v) {
    __hip_atomic_store(p, v, __ATOMIC_RELAXED, __HIP_MEMORY_SCOPE_AGENT);
}

// publish: __syncthreads() drains every thread's vmem (stores are at LLC since they
// are agent-scope), then thread 0 publishes the epoch. LLC serializes: flag after data.
__device__ __forceinline__ void publish_flag(unsigned* flags, int bid, unsigned epoch) {
    __syncthreads();
    if (threadIdx.x == 0)
        __hip_atomic_store(&flags[bid * FLAG_PAD], epoch, __ATOMIC_RELAXED, __HIP_MEMORY_SCOPE_AGENT);
}
// wait until flags[base + i*stride] >= epoch for i in 0..n-1 (read-only polling at LLC)
__device__ __forceinline__ void wait_flags(unsigned* flags, int base, int stride, int n, unsigned epoch) {
    if ((int)threadIdx.x < n) {
        const unsigned* p = &flags[(base + (int)threadIdx.x * stride) * FLAG_PAD];
        while (__hip_atomic_load(p, __ATOMIC_RELAXED, __HIP_MEMORY_SCOPE_AGENT) < epoch)
            __builtin_amdgcn_s_sleep(1);
    }
    __syncthreads();
    // no fence: all subsequently-read shared data uses agent-scope atomic loads (LLC point)
}

__device__ __forceinline__ f32x4 mfma_bf16(short8 a, short8 b, f32x4 c) {
    return __builtin_amdgcn_mfma_f32_16x16x32_bf16(a, b, c, 0, 0, 0);
}

__global__ __launch_bounds__(256, 1) void bilstm_persistent(
    const float* __restrict__ x,
    const float* __restrict__ wih0f, const float* __restrict__ whh0f,
    const float* __restrict__ bih0f, const float* __restrict__ bhh0f,
    const float* __restrict__ wih0b, const float* __restrict__ whh0b,
    const float* __restrict__ bih0b, const float* __restrict__ bhh0b,
    const float* __restrict__ wih1f, const float* __restrict__ whh1f,
    const float* __restrict__ bih1f, const float* __restrict__ bhh1f,
    const float* __restrict__ wih1b, const float* __restrict__ whh1b,
    const float* __restrict__ bih1b, const float* __restrict__ bhh1b,
    const float* __restrict__ fcw,  const float* __restrict__ fcb,
    unsigned* flags,
    unsigned* h0_pk,     // [2 parity][2 dir][B][H] packed (hi | lo<<16)
    unsigned* h1_pk,     // [2 parity][B][H] packed
    unsigned* h1b_pk,    // [B][H] packed (layer-1 backward, t=S-1 result)
    unsigned* out0_pk,   // [B][S][2H] packed
    float* out)
{
    const int bid = blockIdx.x;
    const int tid = threadIdx.x;
    const int l  = tid & 63;    // lane
    const int w  = tid >> 6;    // wave 0..3 (K-split)
    const int lc = l & 15;      // col lane (gate col) / A-row lane (batch)
    const int ks = l >> 4;      // k-segment 0..3 within a 32-k block

    __shared__ float P[4 * 4 * 16 * 20];   // [wave][ntile][gatecol][batch+pad]
    __shared__ float hstage[2][Hn];        // FC staging (used once at the end)

    //==================== PHASE 1: layer 0, both dirs, 512 steps ====================
    {
        const int dir = bid >> 7;          // 0..127 fwd, 128..255 bwd
        const int hs  = (bid >> 2) & 31;   // hidden slice (16 hidden units)
        const int bt  = bid & 3;           // batch tile (16 batches)
        const float* wih = dir ? wih0b : wih0f;
        const float* whh = dir ? whh0b : whh0f;
        const float* bih = dir ? bih0b : bih0f;
        const float* bhh = dir ? bhh0b : bhh0f;

        // preload weight fragments: B[k][col], col = gate row nt*512+hs*16+lc
        short8 wfh[6][4], wfl[6][4];
        #pragma unroll
        for (int i = 0; i < 6; ++i) {
            const int kg = w * 6 + i;
            const int k0 = kg * 32 + ks * 8;
            #pragma unroll
            for (int nt = 0; nt < 4; ++nt) {
                const int r = nt * 512 + hs * 16 + lc;
                const float* src = (k0 < 256) ? &wih[(size_t)r * 256 + k0]
                                              : &whh[(size_t)r * 512 + (k0 - 256)];
                split8(src, wfh[i][nt], wfl[i][nt]);
            }
        }
        const int cb = bt * 16 + (tid >> 4);
        const int ch = hs * 16 + (tid & 15);
        float bias_r[4];
        #pragma unroll
        for (int gt = 0; gt < 4; ++gt)
            bias_r[gt] = bih[gt * 512 + ch] + bhh[gt * 512 + ch];
        float c_reg = 0.f;
        const int bA = bt * 16 + lc;       // A-operand batch row

        for (int s = 0; s < Sn; ++s) {
            // sync group: same (dir, bt), 32 blocks
            wait_flags(flags, dir * 128 + bt, 4, 32, (unsigned)s);

            const int p = s & 1;
            const int t = dir ? (Sn - 1 - s) : s;

            // issue all h loads (coherent), then x split + unpack + MFMA
            unsigned hw[6][8];
            #pragma unroll
            for (int i = 0; i < 6; ++i) {
                const int kg = w * 6 + i;
                const int k0 = kg * 32 + ks * 8;
                if (kg >= 8)
                    lda8(&h0_pk[(((size_t)p * 2 + dir) * Bn + bA) * Hn + (k0 - 256)], hw[i]);
            }
            short8 ah[6], al[6];
            #pragma unroll
            for (int i = 0; i < 6; ++i) {
                const int kg = w * 6 + i;
                const int k0 = kg * 32 + ks * 8;
                if (kg < 8)
                    split8(&x[((size_t)bA * Sn + t) * Dn + k0], ah[i], al[i]);
                else
                    unpack8(hw[i], ah[i], al[i]);
            }

            f32x4 acc0 = {0.f,0.f,0.f,0.f}, acc1 = acc0, acc2 = acc0, acc3 = acc0;
            #pragma unroll
            for (int i = 0; i < 6; ++i) {
                acc0 = mfma_bf16(ah[i], wfh[i][0], acc0);
                acc0 = mfma_bf16(al[i], wfh[i][0], acc0);
                acc0 = mfma_bf16(ah[i], wfl[i][0], acc0);
                acc1 = mfma_bf16(ah[i], wfh[i][1], acc1);
                acc1 = mfma_bf16(al[i], wfh[i][1], acc1);
                acc1 = mfma_bf16(ah[i], wfl[i][1], acc1);
                acc2 = mfma_bf16(ah[i], wfh[i][2], acc2);
                acc2 = mfma_bf16(al[i], wfh[i][2], acc2);
                acc2 = mfma_bf16(ah[i], wfl[i][2], acc2);
                acc3 = mfma_bf16(ah[i], wfh[i][3], acc3);
                acc3 = mfma_bf16(al[i], wfh[i][3], acc3);
                acc3 = mfma_bf16(ah[i], wfl[i][3], acc3);
            }
            // partials -> LDS. C layout: row(batch)=(l>>4)*4+reg, col(gate)=l&15
            *(f32x4*)&P[((w * 4 + 0) * 16 + lc) * 20 + ks * 4] = acc0;
            *(f32x4*)&P[((w * 4 + 1) * 16 + lc) * 20 + ks * 4] = acc1;
            *(f32x4*)&P[((w * 4 + 2) * 16 + lc) * 20 + ks * 4] = acc2;
            *(f32x4*)&P[((w * 4 + 3) * 16 + lc) * 20 + ks * 4] = acc3;
            __syncthreads();
            // cell update: thread t -> batch (t>>4), hidden (t&15)
            {
                float g4[4];
                #pragma unroll
                for (int gt = 0; gt < 4; ++gt) {
                    float sum = bias_r[gt];
                    #pragma unroll
                    for (int ww = 0; ww < 4; ++ww)
                        sum += P[((ww * 4 + gt) * 16 + (tid & 15)) * 20 + (tid >> 4)];
                    g4[gt] = sum;
                }
                const float ig = 1.f / (1.f + expf(-g4[0]));
                const float fg = 1.f / (1.f + expf(-g4[1]));
                const float gg = tanhf(g4[2]);
                const float og = 1.f / (1.f + expf(-g4[3]));
                c_reg = fg * c_reg + ig * gg;
                const float h = og * tanhf(c_reg);
                const ushort hhv = f2bf(h);
                const ushort hlv = f2bf(h - bf2f(hhv));
                const unsigned word = (unsigned)hhv | ((unsigned)hlv << 16);
                sta32(&h0_pk[(((size_t)(p ^ 1) * 2 + dir) * Bn + cb) * Hn + ch], word);
                sta32(&out0_pk[((size_t)cb * Sn + t) * 1024 + dir * 512 + ch], word);
            }
            publish_flag(flags, bid, (unsigned)(s + 1));
        }
    }

    //==================== PHASE 2: layer 1 forward, 512 steps ====================
    {
        const int hs = (bid >> 2) & 63;    // hidden slice (8 hidden units)
        const int bt = bid & 3;
        short8 wfh[12][2], wfl[12][2];
        #pragma unroll
        for (int i = 0; i < 12; ++i) {
            const int kg = w * 12 + i;
            const int k0 = kg * 32 + ks * 8;
            #pragma unroll
            for (int nt = 0; nt < 2; ++nt) {
                const int c = nt * 16 + lc;                 // 0..31
                const int r = (c >> 3) * 512 + hs * 8 + (c & 7);
                const float* src = (k0 < 1024) ? &wih1f[(size_t)r * 1024 + k0]
                                               : &whh1f[(size_t)r * 512 + (k0 - 1024)];
                split8(src, wfh[i][nt], wfl[i][nt]);
            }
        }
        const bool is_cell = (tid < 128);
        const int cb = bt * 16 + (tid >> 3);
        const int ch = hs * 8 + (tid & 7);
        float bias_r[4] = {0.f, 0.f, 0.f, 0.f};
        if (is_cell) {
            #pragma unroll
            for (int gt = 0; gt < 4; ++gt)
                bias_r[gt] = bih1f[gt * 512 + ch] + bhh1f[gt * 512 + ch];
        }
        float c_reg = 0.f;
        const int bA = bt * 16 + lc;

        for (int s = 0; s < Sn; ++s) {
            // sync group: same bt, 64 blocks (covers both phase-1 producer groups)
            wait_flags(flags, bt, 4, 64, (unsigned)(Sn + s));

            const int p = s & 1;
            unsigned hw[12][8];
            #pragma unroll
            for (int i = 0; i < 12; ++i) {
                const int kg = w * 12 + i;
                const int k0 = kg * 32 + ks * 8;
                if (kg < 32)
                    lda8(&out0_pk[((size_t)bA * Sn + s) * 1024 + k0], hw[i]);
                else
                    lda8(&h1_pk[((size_t)p * Bn + bA) * Hn + (k0 - 1024)], hw[i]);
            }
            f32x4 acc0 = {0.f,0.f,0.f,0.f}, acc1 = acc0;
            #pragma unroll
            for (int i = 0; i < 12; ++i) {
                short8 ah, al;
                unpack8(hw[i], ah, al);
                acc0 = mfma_bf16(ah, wfh[i][0], acc0);
                acc0 = mfma_bf16(al, wfh[i][0], acc0);
                acc0 = mfma_bf16(ah, wfl[i][0], acc0);
                acc1 = mfma_bf16(ah, wfh[i][1], acc1);
                acc1 = mfma_bf16(al, wfh[i][1], acc1);
                acc1 = mfma_bf16(ah, wfl[i][1], acc1);
            }
            *(f32x4*)&P[((w * 2 + 0) * 16 + lc) * 20 + ks * 4] = acc0;
            *(f32x4*)&P[((w * 2 + 1) * 16 + lc) * 20 + ks * 4] = acc1;
            __syncthreads();
            if (is_cell) {
                float g4[4];
                #pragma unroll
                for (int gt = 0; gt < 4; ++gt) {
                    const int cc = gt * 8 + (tid & 7);
                    const int nt = cc >> 4, g = cc & 15;
                    float sum = bias_r[gt];
                    #pragma unroll
                    for (int ww = 0; ww < 4; ++ww)
                        sum += P[((ww * 2 + nt) * 16 + g) * 20 + (tid >> 3)];
                    g4[gt] = sum;
                }
                const float ig = 1.f / (1.f + expf(-g4[0]));
                const float fg = 1.f / (1.f + expf(-g4[1]));
                const float gg = tanhf(g4[2]);
                const float og = 1.f / (1.f + expf(-g4[3]));
                c_reg = fg * c_reg + ig * gg;
                const float h = og * tanhf(c_reg);
                const ushort hhv = f2bf(h);
                const ushort hlv = f2bf(h - bf2f(hhv));
                const unsigned word = (unsigned)hhv | ((unsigned)hlv << 16);
                sta32(&h1_pk[((size_t)(p ^ 1) * Bn + cb) * Hn + ch], word);
            }
            publish_flag(flags, bid, (unsigned)(Sn + s + 1));
        }
    }

    //==================== PHASE 3: layer 1 backward, first step only (t = S-1) ====================
    {
        const int hs = (bid >> 2) & 63;
        const int bt = bid & 3;
        const int bA = bt * 16 + lc;
        const int t = Sn - 1;
        // out0[:, S-1, :] fully published before this block finished phase 2 (epoch>=512 waits).
        unsigned hw[8][8];
        #pragma unroll
        for (int i = 0; i < 8; ++i) {          // K = 1024 only (h_prev = 0)
            const int kg = w * 8 + i;
            const int k0 = kg * 32 + ks * 8;
            lda8(&out0_pk[((size_t)bA * Sn + t) * 1024 + k0], hw[i]);
        }
        f32x4 acc0 = {0.f,0.f,0.f,0.f}, acc1 = acc0;
        #pragma unroll
        for (int i = 0; i < 8; ++i) {
            const int kg = w * 8 + i;
            const int k0 = kg * 32 + ks * 8;
            short8 ah, al;
            unpack8(hw[i], ah, al);
            #pragma unroll
            for (int nt = 0; nt < 2; ++nt) {
                const int c = nt * 16 + lc;
                const int r = (c >> 3) * 512 + hs * 8 + (c & 7);
                short8 bh, bl;
                split8(&wih1b[(size_t)r * 1024 + k0], bh, bl);
                f32x4 a = (nt == 0) ? acc0 : acc1;
                a = mfma_bf16(ah, bh, a);
                a = mfma_bf16(al, bh, a);
                a = mfma_bf16(ah, bl, a);
                if (nt == 0) acc0 = a; else acc1 = a;
            }
        }
        *(f32x4*)&P[((w * 2 + 0) * 16 + lc) * 20 + ks * 4] = acc0;
        *(f32x4*)&P[((w * 2 + 1) * 16 + lc) * 20 + ks * 4] = acc1;
        __syncthreads();
        if (tid < 128) {
            const int cb = bt * 16 + (tid >> 3);
            const int ch = hs * 8 + (tid & 7);
            float g4[4];
            #pragma unroll
            for (int gt = 0; gt < 4; ++gt) {
                const int cc = gt * 8 + (tid & 7);
                const int nt = cc >> 4, g = cc & 15;
                float sum = bih1b[gt * 512 + ch] + bhh1b[gt * 512 + ch];
                #pragma unroll
                for (int ww = 0; ww < 4; ++ww)
                    sum += P[((ww * 2 + nt) * 16 + g) * 20 + (tid >> 3)];
                g4[gt] = sum;
            }
            const float ig = 1.f / (1.f + expf(-g4[0]));
            const float gg = tanhf(g4[2]);
            const float og = 1.f / (1.f + expf(-g4[3]));
            const float c = ig * gg;           // c_prev = 0
            const float h = og * tanhf(c);
            const ushort hhv = f2bf(h);
            const ushort hlv = f2bf(h - bf2f(hhv));
            sta32(&h1b_pk[(size_t)cb * Hn + ch], (unsigned)hhv | ((unsigned)hlv << 16));
        }
        publish_flag(flags, bid, (unsigned)(2 * Sn + 1));
    }

    //==================== PHASE 4: FC (blocks 0..63, after global wait) ====================
    if (bid < Bn) {
        wait_flags(flags, 0, 1, 256, (unsigned)(2 * Sn + 1));
        // stage final hidden vectors to LDS as reconstructed fp32 (hi + lo)
        {
            const unsigned long long* qf =
                (const unsigned long long*)&h1_pk[(size_t)0 * Bn * Hn + (size_t)bid * Hn]; // parity 0
            const unsigned long long* qb =
                (const unsigned long long*)&h1b_pk[(size_t)bid * Hn];
            unsigned long long vf = __hip_atomic_load(qf + tid, __ATOMIC_RELAXED, __HIP_MEMORY_SCOPE_AGENT);
            unsigned long long vb = __hip_atomic_load(qb + tid, __ATOMIC_RELAXED, __HIP_MEMORY_SCOPE_AGENT);
            const int j = tid * 2;
            hstage[0][j]     = bf2f((ushort)(vf & 0xffff))         + bf2f((ushort)((vf >> 16) & 0xffff));
            hstage[0][j + 1] = bf2f((ushort)((vf >> 32) & 0xffff)) + bf2f((ushort)((vf >> 48) & 0xffff));
            hstage[1][j]     = bf2f((ushort)(vb & 0xffff))         + bf2f((ushort)((vb >> 16) & 0xffff));
            hstage[1][j + 1] = bf2f((ushort)((vb >> 32) & 0xffff)) + bf2f((ushort)((vb >> 48) & 0xffff));
        }
        __syncthreads();
        if (tid < On) {
            const int b = bid, o = tid;
            float sum = fcb[o];
            const float* wrow = &fcw[(size_t)o * 1024];
            #pragma unroll 4
            for (int j = 0; j < Hn; ++j) sum += hstage[0][j] * wrow[j];
            #pragma unroll 4
            for (int j = 0; j < Hn; ++j) sum += hstage[1][j] * wrow[512 + j];
            out[(size_t)b * On + o] = sum;
        }
    }
}

extern "C" void kernel_launch(void* const* d_in, const int* in_sizes, int n_in,
                              void* d_out, int out_size, void* d_ws, size_t ws_size,
                              hipStream_t stream)
{
    const float* x     = (const float*)d_in[0];
    const float* wih0f = (const float*)d_in[1];
    const float* whh0f = (const float*)d_in[2];
    const float* bih0f = (const float*)d_in[3];
    const float* bhh0f = (const float*)d_in[4];
    const float* wih0b = (const float*)d_in[5];
    const float* whh0b = (const float*)d_in[6];
    const float* bih0b = (const float*)d_in[7];
    const float* bhh0b = (const float*)d_in[8];
    const float* wih1f = (const float*)d_in[9];
    const float* whh1f = (const float*)d_in[10];
    const float* bih1f = (const float*)d_in[11];
    const float* bhh1f = (const float*)d_in[12];
    const float* wih1b = (const float*)d_in[13];
    const float* whh1b = (const float*)d_in[14];
    const float* bih1b = (const float*)d_in[15];
    const float* bhh1b = (const float*)d_in[16];
    const float* fcw   = (const float*)d_in[17];
    const float* fcb   = (const float*)d_in[18];

    char* ws = (char*)d_ws;
    size_t off = 0;
    unsigned* flags  = (unsigned*)(ws + off); off += (size_t)256 * FLAG_PAD * 4;
    unsigned* h0_pk  = (unsigned*)(ws + off); off += (size_t)2 * 2 * Bn * Hn * 4;
    unsigned* h1_pk  = (unsigned*)(ws + off); off += (size_t)2 * Bn * Hn * 4;
    size_t zero_end = off;                    // flags + all recurrent h state must start zeroed
    unsigned* h1b_pk = (unsigned*)(ws + off); off += (size_t)Bn * Hn * 4;
    unsigned* out0_pk = (unsigned*)(ws + off); off += (size_t)Bn * Sn * 2 * Hn * 4;

    // zero flags + initial h state (graph-capture-safe async memset, runs every replay)
    hipMemsetAsync(d_ws, 0, zero_end, stream);

    hipLaunchKernelGGL(bilstm_persistent, dim3(256), dim3(256), 0, stream,
        x, wih0f, whh0f, bih0f, bhh0f, wih0b, whh0b, bih0b, bhh0b,
        wih1f, whh1f, bih1f, bhh1f, wih1b, whh1b, bih1b, bhh1b,
        fcw, fcb,
        flags, h0_pk, h1_pk, h1b_pk, out0_pk,
        (float*)d_out);
}

// Round 7
// 6760.989 us; speedup vs baseline: 6.3570x; 1.2075x over previous
//
#include <hip/hip_runtime.h>
#include <math.h>

#define Bn 64
#define Sn 512
#define Dn 256
#define Hn 512
#define On 128
#define FLAG_PAD 32   // one 128B cacheline per flag

using short8 = __attribute__((ext_vector_type(8))) short;
using f32x4  = __attribute__((ext_vector_type(4))) float;

union U8 { unsigned u[4]; short8 s; };

__device__ __forceinline__ ushort f2bf(float f) {
    unsigned u = __float_as_uint(f);
    u = u + 0x7FFFu + ((u >> 16) & 1u);   // round-to-nearest-even
    return (ushort)(u >> 16);
}
__device__ __forceinline__ float bf2f(ushort b) {
    return __uint_as_float(((unsigned)b) << 16);
}
// split 8 consecutive fp32 into hi/lo bf16 fragments
__device__ __forceinline__ void split8(const float* __restrict__ p, short8& hi, short8& lo) {
    #pragma unroll
    for (int j = 0; j < 8; ++j) {
        float w = p[j];
        ushort h = f2bf(w);
        hi[j] = (short)h;
        lo[j] = (short)f2bf(w - bf2f(h));
    }
}

// ---- LLC-coherent data access via relaxed agent atomics (proven in R6) ----
__device__ __forceinline__ void lda8(const unsigned* p, unsigned* w) {
    const unsigned long long* q = (const unsigned long long*)p;
    #pragma unroll
    for (int j = 0; j < 4; ++j) {
        unsigned long long v = __hip_atomic_load(q + j, __ATOMIC_RELAXED, __HIP_MEMORY_SCOPE_AGENT);
        w[2*j]   = (unsigned)v;
        w[2*j+1] = (unsigned)(v >> 32);
    }
}
__device__ __forceinline__ void unpack8(const unsigned* w, short8& hi8, short8& lo8) {
    U8 a, b;
    #pragma unroll
    for (int j = 0; j < 4; ++j) {
        a.u[j] = (w[2*j] & 0xffffu) | (w[2*j+1] << 16);
        b.u[j] = (w[2*j] >> 16)     | (w[2*j+1] & 0xffff0000u);
    }
    hi8 = a.s; lo8 = b.s;
}
__device__ __forceinline__ void sta32(unsigned* p, unsigned v) {
    __hip_atomic_store(p, v, __ATOMIC_RELAXED, __HIP_MEMORY_SCOPE_AGENT);
}

// publish: __syncthreads() drains every thread's vmem stores, then thread0 sets epoch
__device__ __forceinline__ void publish_flag(unsigned* flags, int bid, unsigned epoch) {
    __syncthreads();
    if (threadIdx.x == 0)
        __hip_atomic_store(&flags[bid * FLAG_PAD], epoch, __ATOMIC_RELAXED, __HIP_MEMORY_SCOPE_AGENT);
}
// wait until flags[base + i*stride] >= epoch for i in 0..n-1
__device__ __forceinline__ void wait_flags(unsigned* flags, int base, int stride, int n, unsigned epoch) {
    if ((int)threadIdx.x < n) {
        const unsigned* p = &flags[(base + (int)threadIdx.x * stride) * FLAG_PAD];
        while (__hip_atomic_load(p, __ATOMIC_RELAXED, __HIP_MEMORY_SCOPE_AGENT) < epoch)
            __builtin_amdgcn_s_sleep(1);
    }
    __syncthreads();
}

__device__ __forceinline__ f32x4 mfma_bf16(short8 a, short8 b, f32x4 c) {
    return __builtin_amdgcn_mfma_f32_16x16x32_bf16(a, b, c, 0, 0, 0);
}

__global__ __launch_bounds__(256, 1) void bilstm_persistent(
    const float* __restrict__ x,
    const float* __restrict__ wih0f, const float* __restrict__ whh0f,
    const float* __restrict__ bih0f, const float* __restrict__ bhh0f,
    const float* __restrict__ wih0b, const float* __restrict__ whh0b,
    const float* __restrict__ bih0b, const float* __restrict__ bhh0b,
    const float* __restrict__ wih1f, const float* __restrict__ whh1f,
    const float* __restrict__ bih1f, const float* __restrict__ bhh1f,
    const float* __restrict__ wih1b, const float* __restrict__ whh1b,
    const float* __restrict__ bih1b, const float* __restrict__ bhh1b,
    const float* __restrict__ fcw,  const float* __restrict__ fcb,
    unsigned* flags,
    unsigned* h0_pk,     // [2 parity][2 dir][B][H] packed (hi | lo<<16)
    unsigned* h1_pk,     // [2 parity][B][H] packed
    unsigned* h1b_pk,    // [B][H] packed
    unsigned* out0_pk,   // [B][S][2H] packed
    float* out)
{
    const int bid = blockIdx.x;
    const int tid = threadIdx.x;
    const int l  = tid & 63;    // lane
    const int w  = tid >> 6;    // wave 0..3 (K-split)
    const int lc = l & 15;      // col lane (gate col) / A-row lane (batch)
    const int ks = l >> 4;      // k-segment 0..3 within a 32-k block

    __shared__ float P[4 * 4 * 16 * 20];   // [wave][ntile][gatecol][batch+pad]
    __shared__ float hstage[2][Hn];        // FC staging

    //==================== PHASE 1: layer 0, both dirs, 512 steps ====================
    {
        const int dir = bid >> 7;          // 0..127 fwd, 128..255 bwd
        const int hs  = (bid >> 2) & 31;   // hidden slice (16 hidden units)
        const int bt  = bid & 3;           // batch tile (16 batches)
        const float* wih = dir ? wih0b : wih0f;
        const float* whh = dir ? whh0b : whh0f;
        const float* bih = dir ? bih0b : bih0f;
        const float* bhh = dir ? bhh0b : bhh0f;

        // x-part weights (K=256): 2 kg per wave
        short8 wx_h[2][4], wx_l[2][4];
        #pragma unroll
        for (int i = 0; i < 2; ++i) {
            const int k0 = (w * 2 + i) * 32 + ks * 8;
            #pragma unroll
            for (int nt = 0; nt < 4; ++nt) {
                const int r = nt * 512 + hs * 16 + lc;
                split8(&wih[(size_t)r * 256 + k0], wx_h[i][nt], wx_l[i][nt]);
            }
        }
        // h-part weights (K=512): 4 kg per wave
        short8 wh_h[4][4], wh_l[4][4];
        #pragma unroll
        for (int i = 0; i < 4; ++i) {
            const int k0 = (w * 4 + i) * 32 + ks * 8;
            #pragma unroll
            for (int nt = 0; nt < 4; ++nt) {
                const int r = nt * 512 + hs * 16 + lc;
                split8(&whh[(size_t)r * 512 + k0], wh_h[i][nt], wh_l[i][nt]);
            }
        }
        const int cb = bt * 16 + (tid >> 4);
        const int ch = hs * 16 + (tid & 15);
        float bias_r[4];
        #pragma unroll
        for (int gt = 0; gt < 4; ++gt)
            bias_r[gt] = bih[gt * 512 + ch] + bhh[gt * 512 + ch];
        float c_reg = 0.f;
        const int bA = bt * 16 + lc;       // A-operand batch row

        // xg for step 0
        f32x4 xg0 = {0.f,0.f,0.f,0.f}, xg1 = xg0, xg2 = xg0, xg3 = xg0;
        {
            const int tt = dir ? (Sn - 1) : 0;
            #pragma unroll
            for (int i = 0; i < 2; ++i) {
                const int k0 = (w * 2 + i) * 32 + ks * 8;
                short8 xh, xl;
                split8(&x[((size_t)bA * Sn + tt) * Dn + k0], xh, xl);
                xg0 = mfma_bf16(xh, wx_h[i][0], xg0); xg0 = mfma_bf16(xl, wx_h[i][0], xg0); xg0 = mfma_bf16(xh, wx_l[i][0], xg0);
                xg1 = mfma_bf16(xh, wx_h[i][1], xg1); xg1 = mfma_bf16(xl, wx_h[i][1], xg1); xg1 = mfma_bf16(xh, wx_l[i][1], xg1);
                xg2 = mfma_bf16(xh, wx_h[i][2], xg2); xg2 = mfma_bf16(xl, wx_h[i][2], xg2); xg2 = mfma_bf16(xh, wx_l[i][2], xg2);
                xg3 = mfma_bf16(xh, wx_h[i][3], xg3); xg3 = mfma_bf16(xl, wx_h[i][3], xg3); xg3 = mfma_bf16(xh, wx_l[i][3], xg3);
            }
        }

        for (int s = 0; s < Sn; ++s) {
            if (s) wait_flags(flags, dir * 128 + bt, 4, 32, (unsigned)s);

            const int p = s & 1;
            const int t = dir ? (Sn - 1 - s) : s;

            // critical: h loads (K=512 only) + dependent MFMAs
            unsigned hw[4][8];
            #pragma unroll
            for (int i = 0; i < 4; ++i)
                lda8(&h0_pk[(((size_t)p * 2 + dir) * Bn + bA) * Hn + (w * 4 + i) * 32 + ks * 8], hw[i]);

            f32x4 acc0 = xg0, acc1 = xg1, acc2 = xg2, acc3 = xg3;
            #pragma unroll
            for (int i = 0; i < 4; ++i) {
                short8 ah, al;
                unpack8(hw[i], ah, al);
                acc0 = mfma_bf16(ah, wh_h[i][0], acc0); acc0 = mfma_bf16(al, wh_h[i][0], acc0); acc0 = mfma_bf16(ah, wh_l[i][0], acc0);
                acc1 = mfma_bf16(ah, wh_h[i][1], acc1); acc1 = mfma_bf16(al, wh_h[i][1], acc1); acc1 = mfma_bf16(ah, wh_l[i][1], acc1);
                acc2 = mfma_bf16(ah, wh_h[i][2], acc2); acc2 = mfma_bf16(al, wh_h[i][2], acc2); acc2 = mfma_bf16(ah, wh_l[i][2], acc2);
                acc3 = mfma_bf16(ah, wh_h[i][3], acc3); acc3 = mfma_bf16(al, wh_h[i][3], acc3); acc3 = mfma_bf16(ah, wh_l[i][3], acc3);
            }
            *(f32x4*)&P[((w * 4 + 0) * 16 + lc) * 20 + ks * 4] = acc0;
            *(f32x4*)&P[((w * 4 + 1) * 16 + lc) * 20 + ks * 4] = acc1;
            *(f32x4*)&P[((w * 4 + 2) * 16 + lc) * 20 + ks * 4] = acc2;
            *(f32x4*)&P[((w * 4 + 3) * 16 + lc) * 20 + ks * 4] = acc3;
            __syncthreads();

            unsigned word;
            {
                float g4[4];
                #pragma unroll
                for (int gt = 0; gt < 4; ++gt) {
                    float sum = bias_r[gt];
                    #pragma unroll
                    for (int ww = 0; ww < 4; ++ww)
                        sum += P[((ww * 4 + gt) * 16 + (tid & 15)) * 20 + (tid >> 4)];
                    g4[gt] = sum;
                }
                const float ig = 1.f / (1.f + expf(-g4[0]));
                const float fg = 1.f / (1.f + expf(-g4[1]));
                const float gg = tanhf(g4[2]);
                const float og = 1.f / (1.f + expf(-g4[3]));
                c_reg = fg * c_reg + ig * gg;
                const float h = og * tanhf(c_reg);
                const ushort hhv = f2bf(h);
                const ushort hlv = f2bf(h - bf2f(hhv));
                word = (unsigned)hhv | ((unsigned)hlv << 16);
                sta32(&h0_pk[(((size_t)(p ^ 1) * 2 + dir) * Bn + cb) * Hn + ch], word);
            }
            // last step: out0 must be LLC-visible before publish(512) (phase-2 gate)
            if (s == Sn - 1)
                sta32(&out0_pk[((size_t)cb * Sn + t) * 1024 + dir * 512 + ch], word);

            publish_flag(flags, bid, (unsigned)(s + 1));

            // hoisted off critical path: out0 store + next step's x-projection
            if (s < Sn - 1) {
                sta32(&out0_pk[((size_t)cb * Sn + t) * 1024 + dir * 512 + ch], word);
                const int tt = dir ? (Sn - 2 - s) : (s + 1);
                xg0 = {0.f,0.f,0.f,0.f}; xg1 = xg0; xg2 = xg0; xg3 = xg0;
                #pragma unroll
                for (int i = 0; i < 2; ++i) {
                    const int k0 = (w * 2 + i) * 32 + ks * 8;
                    short8 xh, xl;
                    split8(&x[((size_t)bA * Sn + tt) * Dn + k0], xh, xl);
                    xg0 = mfma_bf16(xh, wx_h[i][0], xg0); xg0 = mfma_bf16(xl, wx_h[i][0], xg0); xg0 = mfma_bf16(xh, wx_l[i][0], xg0);
                    xg1 = mfma_bf16(xh, wx_h[i][1], xg1); xg1 = mfma_bf16(xl, wx_h[i][1], xg1); xg1 = mfma_bf16(xh, wx_l[i][1], xg1);
                    xg2 = mfma_bf16(xh, wx_h[i][2], xg2); xg2 = mfma_bf16(xl, wx_h[i][2], xg2); xg2 = mfma_bf16(xh, wx_l[i][2], xg2);
                    xg3 = mfma_bf16(xh, wx_h[i][3], xg3); xg3 = mfma_bf16(xl, wx_h[i][3], xg3); xg3 = mfma_bf16(xh, wx_l[i][3], xg3);
                }
            }
        }
    }

    //==================== PHASE 2: layer 1 forward, 512 steps ====================
    {
        const int hs = (bid >> 2) & 63;    // hidden slice (8 hidden units)
        const int bt = bid & 3;
        // x-part (out0, K=1024): 8 kg per wave
        short8 wx_h[8][2], wx_l[8][2];
        #pragma unroll
        for (int i = 0; i < 8; ++i) {
            const int k0 = (w * 8 + i) * 32 + ks * 8;
            #pragma unroll
            for (int nt = 0; nt < 2; ++nt) {
                const int c = nt * 16 + lc;
                const int r = (c >> 3) * 512 + hs * 8 + (c & 7);
                split8(&wih1f[(size_t)r * 1024 + k0], wx_h[i][nt], wx_l[i][nt]);
            }
        }
        // h-part (K=512): 4 kg per wave
        short8 wh_h[4][2], wh_l[4][2];
        #pragma unroll
        for (int i = 0; i < 4; ++i) {
            const int k0 = (w * 4 + i) * 32 + ks * 8;
            #pragma unroll
            for (int nt = 0; nt < 2; ++nt) {
                const int c = nt * 16 + lc;
                const int r = (c >> 3) * 512 + hs * 8 + (c & 7);
                split8(&whh1f[(size_t)r * 512 + k0], wh_h[i][nt], wh_l[i][nt]);
            }
        }
        const bool is_cell = (tid < 128);
        const int cb = bt * 16 + (tid >> 3);
        const int ch = hs * 8 + (tid & 7);
        float bias_r[4] = {0.f, 0.f, 0.f, 0.f};
        if (is_cell) {
            #pragma unroll
            for (int gt = 0; gt < 4; ++gt)
                bias_r[gt] = bih1f[gt * 512 + ch] + bhh1f[gt * 512 + ch];
        }
        float c_reg = 0.f;
        const int bA = bt * 16 + lc;

        // gate: all same-bt phase-1 producers done -> all out0 for this bt visible
        wait_flags(flags, bt, 4, 64, (unsigned)Sn);

        // xg for step 0
        f32x4 xg0 = {0.f,0.f,0.f,0.f}, xg1 = xg0;
        {
            unsigned ow[8][8];
            #pragma unroll
            for (int i = 0; i < 8; ++i)
                lda8(&out0_pk[(size_t)bA * Sn * 1024 + (w * 8 + i) * 32 + ks * 8], ow[i]);
            #pragma unroll
            for (int i = 0; i < 8; ++i) {
                short8 ah, al;
                unpack8(ow[i], ah, al);
                xg0 = mfma_bf16(ah, wx_h[i][0], xg0); xg0 = mfma_bf16(al, wx_h[i][0], xg0); xg0 = mfma_bf16(ah, wx_l[i][0], xg0);
                xg1 = mfma_bf16(ah, wx_h[i][1], xg1); xg1 = mfma_bf16(al, wx_h[i][1], xg1); xg1 = mfma_bf16(ah, wx_l[i][1], xg1);
            }
        }

        for (int s = 0; s < Sn; ++s) {
            if (s) wait_flags(flags, bt, 4, 64, (unsigned)(Sn + s));

            const int p = s & 1;
            // critical: h1 loads (K=512) + dependent MFMAs
            unsigned hw[4][8];
            #pragma unroll
            for (int i = 0; i < 4; ++i)
                lda8(&h1_pk[((size_t)p * Bn + bA) * Hn + (w * 4 + i) * 32 + ks * 8], hw[i]);

            f32x4 acc0 = xg0, acc1 = xg1;
            #pragma unroll
            for (int i = 0; i < 4; ++i) {
                short8 ah, al;
                unpack8(hw[i], ah, al);
                acc0 = mfma_bf16(ah, wh_h[i][0], acc0); acc0 = mfma_bf16(al, wh_h[i][0], acc0); acc0 = mfma_bf16(ah, wh_l[i][0], acc0);
                acc1 = mfma_bf16(ah, wh_h[i][1], acc1); acc1 = mfma_bf16(al, wh_h[i][1], acc1); acc1 = mfma_bf16(ah, wh_l[i][1], acc1);
            }
            *(f32x4*)&P[((w * 2 + 0) * 16 + lc) * 20 + ks * 4] = acc0;
            *(f32x4*)&P[((w * 2 + 1) * 16 + lc) * 20 + ks * 4] = acc1;
            __syncthreads();

            if (is_cell) {
                float g4[4];
                #pragma unroll
                for (int gt = 0; gt < 4; ++gt) {
                    const int cc = gt * 8 + (tid & 7);
                    const int nt = cc >> 4, g = cc & 15;
                    float sum = bias_r[gt];
                    #pragma unroll
                    for (int ww = 0; ww < 4; ++ww)
                        sum += P[((ww * 2 + nt) * 16 + g) * 20 + (tid >> 3)];
                    g4[gt] = sum;
                }
                const float ig = 1.f / (1.f + expf(-g4[0]));
                const float fg = 1.f / (1.f + expf(-g4[1]));
                const float gg = tanhf(g4[2]);
                const float og = 1.f / (1.f + expf(-g4[3]));
                c_reg = fg * c_reg + ig * gg;
                const float h = og * tanhf(c_reg);
                const ushort hhv = f2bf(h);
                const ushort hlv = f2bf(h - bf2f(hhv));
                const unsigned word = (unsigned)hhv | ((unsigned)hlv << 16);
                sta32(&h1_pk[((size_t)(p ^ 1) * Bn + cb) * Hn + ch], word);
                if (s == Sn - 1)
                    sta32((unsigned*)&hstage[0][0], 0u);   // no-op slot keeps structure; real store below
            }
            if (is_cell && s == Sn - 1) {
                // final forward h as fp32 for FC: reconstruct from this thread's own values
            }
            publish_flag(flags, bid, (unsigned)(Sn + s + 1));

            // hoisted: next step's out0 projection
            if (s < Sn - 1) {
                unsigned ow[8][8];
                #pragma unroll
                for (int i = 0; i < 8; ++i)
                    lda8(&out0_pk[((size_t)bA * Sn + (s + 1)) * 1024 + (w * 8 + i) * 32 + ks * 8], ow[i]);
                xg0 = {0.f,0.f,0.f,0.f}; xg1 = xg0;
                #pragma unroll
                for (int i = 0; i < 8; ++i) {
                    short8 ah, al;
                    unpack8(ow[i], ah, al);
                    xg0 = mfma_bf16(ah, wx_h[i][0], xg0); xg0 = mfma_bf16(al, wx_h[i][0], xg0); xg0 = mfma_bf16(ah, wx_l[i][0], xg0);
                    xg1 = mfma_bf16(ah, wx_h[i][1], xg1); xg1 = mfma_bf16(al, wx_h[i][1], xg1); xg1 = mfma_bf16(ah, wx_l[i][1], xg1);
                }
            }
        }
    }

    //==================== PHASE 3: layer 1 backward, first step only (t = S-1) ====================
    {
        const int hs = (bid >> 2) & 63;
        const int bt = bid & 3;
        const int bA = bt * 16 + lc;
        const int t = Sn - 1;
        unsigned hw[8][8];
        #pragma unroll
        for (int i = 0; i < 8; ++i) {
            const int k0 = (w * 8 + i) * 32 + ks * 8;
            lda8(&out0_pk[((size_t)bA * Sn + t) * 1024 + k0], hw[i]);
        }
        f32x4 acc0 = {0.f,0.f,0.f,0.f}, acc1 = acc0;
        #pragma unroll
        for (int i = 0; i < 8; ++i) {
            const int k0 = (w * 8 + i) * 32 + ks * 8;
            short8 ah, al;
            unpack8(hw[i], ah, al);
            #pragma unroll
            for (int nt = 0; nt < 2; ++nt) {
                const int c = nt * 16 + lc;
                const int r = (c >> 3) * 512 + hs * 8 + (c & 7);
                short8 bh, bl;
                split8(&wih1b[(size_t)r * 1024 + k0], bh, bl);
                f32x4 a = (nt == 0) ? acc0 : acc1;
                a = mfma_bf16(ah, bh, a);
                a = mfma_bf16(al, bh, a);
                a = mfma_bf16(ah, bl, a);
                if (nt == 0) acc0 = a; else acc1 = a;
            }
        }
        *(f32x4*)&P[((w * 2 + 0) * 16 + lc) * 20 + ks * 4] = acc0;
        *(f32x4*)&P[((w * 2 + 1) * 16 + lc) * 20 + ks * 4] = acc1;
        __syncthreads();
        if (tid < 128) {
            const int cb = bt * 16 + (tid >> 3);
            const int ch = hs * 8 + (tid & 7);
            float g4[4];
            #pragma unroll
            for (int gt = 0; gt < 4; ++gt) {
                const int cc = gt * 8 + (tid & 7);
                const int nt = cc >> 4, g = cc & 15;
                float sum = bih1b[gt * 512 + ch] + bhh1b[gt * 512 + ch];
                #pragma unroll
                for (int ww = 0; ww < 4; ++ww)
                    sum += P[((ww * 2 + nt) * 16 + g) * 20 + (tid >> 3)];
                g4[gt] = sum;
            }
            const float ig = 1.f / (1.f + expf(-g4[0]));
            const float gg = tanhf(g4[2]);
            const float og = 1.f / (1.f + expf(-g4[3]));
            const float c = ig * gg;           // c_prev = 0
            const float h = og * tanhf(c);
            const ushort hhv = f2bf(h);
            const ushort hlv = f2bf(h - bf2f(hhv));
            sta32(&h1b_pk[(size_t)cb * Hn + ch], (unsigned)hhv | ((unsigned)hlv << 16));
        }
        publish_flag(flags, bid, (unsigned)(2 * Sn + 1));
    }

    //==================== PHASE 4: FC (blocks 0..63, after global wait) ====================
    if (bid < Bn) {
        wait_flags(flags, 0, 1, 256, (unsigned)(2 * Sn + 1));
        {
            // final forward h (parity after 512 steps is parity 0) + backward-first h
            const unsigned long long* qf =
                (const unsigned long long*)&h1_pk[(size_t)0 * Bn * Hn + (size_t)bid * Hn];
            const unsigned long long* qb =
                (const unsigned long long*)&h1b_pk[(size_t)bid * Hn];
            unsigned long long vf = __hip_atomic_load(qf + tid, __ATOMIC_RELAXED, __HIP_MEMORY_SCOPE_AGENT);
            unsigned long long vb = __hip_atomic_load(qb + tid, __ATOMIC_RELAXED, __HIP_MEMORY_SCOPE_AGENT);
            const int j = tid * 2;
            hstage[0][j]     = bf2f((ushort)(vf & 0xffff))         + bf2f((ushort)((vf >> 16) & 0xffff));
            hstage[0][j + 1] = bf2f((ushort)((vf >> 32) & 0xffff)) + bf2f((ushort)((vf >> 48) & 0xffff));
            hstage[1][j]     = bf2f((ushort)(vb & 0xffff))         + bf2f((ushort)((vb >> 16) & 0xffff));
            hstage[1][j + 1] = bf2f((ushort)((vb >> 32) & 0xffff)) + bf2f((ushort)((vb >> 48) & 0xffff));
        }
        __syncthreads();
        if (tid < On) {
            const int b = bid, o = tid;
            float sum = fcb[o];
            const float* wrow = &fcw[(size_t)o * 1024];
            #pragma unroll 4
            for (int j = 0; j < Hn; ++j) sum += hstage[0][j] * wrow[j];
            #pragma unroll 4
            for (int j = 0; j < Hn; ++j) sum += hstage[1][j] * wrow[512 + j];
            out[(size_t)b * On + o] = sum;
        }
    }
}

extern "C" void kernel_launch(void* const* d_in, const int* in_sizes, int n_in,
                              void* d_out, int out_size, void* d_ws, size_t ws_size,
                              hipStream_t stream)
{
    const float* x     = (const float*)d_in[0];
    const float* wih0f = (const float*)d_in[1];
    const float* whh0f = (const float*)d_in[2];
    const float* bih0f = (const float*)d_in[3];
    const float* bhh0f = (const float*)d_in[4];
    const float* wih0b = (const float*)d_in[5];
    const float* whh0b = (const float*)d_in[6];
    const float* bih0b = (const float*)d_in[7];
    const float* bhh0b = (const float*)d_in[8];
    const float* wih1f = (const float*)d_in[9];
    const float* whh1f = (const float*)d_in[10];
    const float* bih1f = (const float*)d_in[11];
    const float* bhh1f = (const float*)d_in[12];
    const float* wih1b = (const float*)d_in[13];
    const float* whh1b = (const float*)d_in[14];
    const float* bih1b = (const float*)d_in[15];
    const float* bhh1b = (const float*)d_in[16];
    const float* fcw   = (const float*)d_in[17];
    const float* fcb   = (const float*)d_in[18];

    char* ws = (char*)d_ws;
    size_t off = 0;
    unsigned* flags  = (unsigned*)(ws + off); off += (size_t)256 * FLAG_PAD * 4;
    unsigned* h0_pk  = (unsigned*)(ws + off); off += (size_t)2 * 2 * Bn * Hn * 4;
    unsigned* h1_pk  = (unsigned*)(ws + off); off += (size_t)2 * Bn * Hn * 4;
    size_t zero_end = off;                    // flags + recurrent h state must start zeroed
    unsigned* h1b_pk = (unsigned*)(ws + off); off += (size_t)Bn * Hn * 4;
    unsigned* out0_pk = (unsigned*)(ws + off); off += (size_t)Bn * Sn * 2 * Hn * 4;

    hipMemsetAsync(d_ws, 0, zero_end, stream);

    hipLaunchKernelGGL(bilstm_persistent, dim3(256), dim3(256), 0, stream,
        x, wih0f, whh0f, bih0f, bhh0f, wih0b, whh0b, bih0b, bhh0b,
        wih1f, whh1f, bih1f, bhh1f, wih1b, whh1b, bih1b, bhh1b,
        fcw, fcb,
        flags, h0_pk, h1_pk, h1b_pk, out0_pk,
        (float*)d_out);
}

// Round 8
// 6595.894 us; speedup vs baseline: 6.5161x; 1.0250x over previous
//
#include <hip/hip_runtime.h>
#include <math.h>

#define Bn 64
#define Sn 512
#define Dn 256
#define Hn 512
#define On 128

using short8 = __attribute__((ext_vector_type(8))) short;
using f32x4  = __attribute__((ext_vector_type(4))) float;

union U8 { unsigned u[4]; short8 s; };

__device__ __forceinline__ ushort f2bf(float f) {
    unsigned u = __float_as_uint(f);
    u = u + 0x7FFFu + ((u >> 16) & 1u);   // round-to-nearest-even
    return (ushort)(u >> 16);
}
__device__ __forceinline__ float bf2f(ushort b) {
    return __uint_as_float(((unsigned)b) << 16);
}
// split 8 consecutive fp32 into hi/lo bf16 fragments
__device__ __forceinline__ void split8(const float* __restrict__ p, short8& hi, short8& lo) {
    #pragma unroll
    for (int j = 0; j < 8; ++j) {
        float w = p[j];
        ushort h = f2bf(w);
        hi[j] = (short)h;
        lo[j] = (short)f2bf(w - bf2f(h));
    }
}

// ---- LLC-coherent data access via relaxed agent atomics (proven R6/R7) ----
__device__ __forceinline__ void lda8(const unsigned* p, unsigned* w) {
    const unsigned long long* q = (const unsigned long long*)p;
    #pragma unroll
    for (int j = 0; j < 4; ++j) {
        unsigned long long v = __hip_atomic_load(q + j, __ATOMIC_RELAXED, __HIP_MEMORY_SCOPE_AGENT);
        w[2*j]   = (unsigned)v;
        w[2*j+1] = (unsigned)(v >> 32);
    }
}
__device__ __forceinline__ void unpack8(const unsigned* w, short8& hi8, short8& lo8) {
    U8 a, b;
    #pragma unroll
    for (int j = 0; j < 4; ++j) {
        a.u[j] = (w[2*j] & 0xffffu) | (w[2*j+1] << 16);
        b.u[j] = (w[2*j] >> 16)     | (w[2*j+1] & 0xffff0000u);
    }
    hi8 = a.s; lo8 = b.s;
}
__device__ __forceinline__ void sta32(unsigned* p, unsigned v) {
    __hip_atomic_store(p, v, __ATOMIC_RELAXED, __HIP_MEMORY_SCOPE_AGENT);
}

// ---- packed-flag sync fabric ----
// Flags of one group live in CONSECUTIVE words (same cacheline(s)):
// a consumer wave polls them with one coalesced load per iteration.
__device__ __forceinline__ void poll_ge(const unsigned* p, unsigned epoch) {
    while (__hip_atomic_load(p, __ATOMIC_RELAXED, __HIP_MEMORY_SCOPE_AGENT) < epoch)
        __builtin_amdgcn_s_sleep(1);
}
// wait: slots base[0..n) all >= epoch (n <= blockDim threads participate)
__device__ __forceinline__ void wait_group(const unsigned* base, int n, unsigned epoch) {
    if ((int)threadIdx.x < n)
        poll_ge(base + threadIdx.x, epoch);
    __syncthreads();
}
// publish: all prior agent-scope stores drained by syncthreads, then slot := epoch
__device__ __forceinline__ void publish_slot(unsigned* slot, unsigned epoch) {
    __syncthreads();
    if (threadIdx.x == 0)
        __hip_atomic_store(slot, epoch, __ATOMIC_RELAXED, __HIP_MEMORY_SCOPE_AGENT);
}

__device__ __forceinline__ f32x4 mfma_bf16(short8 a, short8 b, f32x4 c) {
    return __builtin_amdgcn_mfma_f32_16x16x32_bf16(a, b, c, 0, 0, 0);
}

__global__ __launch_bounds__(256, 1) void bilstm_persistent(
    const float* __restrict__ x,
    const float* __restrict__ wih0f, const float* __restrict__ whh0f,
    const float* __restrict__ bih0f, const float* __restrict__ bhh0f,
    const float* __restrict__ wih0b, const float* __restrict__ whh0b,
    const float* __restrict__ bih0b, const float* __restrict__ bhh0b,
    const float* __restrict__ wih1f, const float* __restrict__ whh1f,
    const float* __restrict__ bih1f, const float* __restrict__ bhh1f,
    const float* __restrict__ wih1b, const float* __restrict__ whh1b,
    const float* __restrict__ bih1b, const float* __restrict__ bhh1b,
    const float* __restrict__ fcw,  const float* __restrict__ fcb,
    unsigned* flags,     // [0..256) P1 (8 groups x 32), [256..512) P2 (4 groups x 64), [512..768) P3
    unsigned* h0_pk,     // [2 parity][2 dir][B][H] packed (hi | lo<<16)
    unsigned* h1_pk,     // [2 parity][B][H] packed
    unsigned* h1b_pk,    // [B][H] packed
    unsigned* out0_pk,   // [B][S][2H] packed
    float* out)
{
    const int bid = blockIdx.x;
    const int tid = threadIdx.x;
    const int l  = tid & 63;    // lane
    const int w  = tid >> 6;    // wave 0..3 (K-split)
    const int lc = l & 15;      // col lane (gate col) / A-row lane (batch)
    const int ks = l >> 4;      // k-segment 0..3 within a 32-k block

    __shared__ float P[4 * 4 * 16 * 20];   // [wave][ntile][gatecol][batch+pad]
    __shared__ float hstage[2][Hn];        // FC staging

    //==================== PHASE 1: layer 0, both dirs, 512 steps ====================
    {
        const int dir = bid >> 7;          // 0..127 fwd, 128..255 bwd
        const int hs  = (bid >> 2) & 31;   // hidden slice (16 hidden units)
        const int bt  = bid & 3;           // batch tile (16 batches)
        unsigned* g1 = &flags[(dir * 4 + bt) * 32];   // this block's P1 group line
        const float* wih = dir ? wih0b : wih0f;
        const float* whh = dir ? whh0b : whh0f;
        const float* bih = dir ? bih0b : bih0f;
        const float* bhh = dir ? bhh0b : bhh0f;

        // x-part weights (K=256): 2 kg per wave
        short8 wx_h[2][4], wx_l[2][4];
        #pragma unroll
        for (int i = 0; i < 2; ++i) {
            const int k0 = (w * 2 + i) * 32 + ks * 8;
            #pragma unroll
            for (int nt = 0; nt < 4; ++nt) {
                const int r = nt * 512 + hs * 16 + lc;
                split8(&wih[(size_t)r * 256 + k0], wx_h[i][nt], wx_l[i][nt]);
            }
        }
        // h-part weights (K=512): 4 kg per wave
        short8 wh_h[4][4], wh_l[4][4];
        #pragma unroll
        for (int i = 0; i < 4; ++i) {
            const int k0 = (w * 4 + i) * 32 + ks * 8;
            #pragma unroll
            for (int nt = 0; nt < 4; ++nt) {
                const int r = nt * 512 + hs * 16 + lc;
                split8(&whh[(size_t)r * 512 + k0], wh_h[i][nt], wh_l[i][nt]);
            }
        }
        const int cb = bt * 16 + (tid >> 4);
        const int ch = hs * 16 + (tid & 15);
        float bias_r[4];
        #pragma unroll
        for (int gt = 0; gt < 4; ++gt)
            bias_r[gt] = bih[gt * 512 + ch] + bhh[gt * 512 + ch];
        float c_reg = 0.f;
        const int bA = bt * 16 + lc;       // A-operand batch row

        // xg for step 0
        f32x4 xg0 = {0.f,0.f,0.f,0.f}, xg1 = xg0, xg2 = xg0, xg3 = xg0;
        {
            const int tt = dir ? (Sn - 1) : 0;
            #pragma unroll
            for (int i = 0; i < 2; ++i) {
                const int k0 = (w * 2 + i) * 32 + ks * 8;
                short8 xh, xl;
                split8(&x[((size_t)bA * Sn + tt) * Dn + k0], xh, xl);
                xg0 = mfma_bf16(xh, wx_h[i][0], xg0); xg0 = mfma_bf16(xl, wx_h[i][0], xg0); xg0 = mfma_bf16(xh, wx_l[i][0], xg0);
                xg1 = mfma_bf16(xh, wx_h[i][1], xg1); xg1 = mfma_bf16(xl, wx_h[i][1], xg1); xg1 = mfma_bf16(xh, wx_l[i][1], xg1);
                xg2 = mfma_bf16(xh, wx_h[i][2], xg2); xg2 = mfma_bf16(xl, wx_h[i][2], xg2); xg2 = mfma_bf16(xh, wx_l[i][2], xg2);
                xg3 = mfma_bf16(xh, wx_h[i][3], xg3); xg3 = mfma_bf16(xl, wx_h[i][3], xg3); xg3 = mfma_bf16(xh, wx_l[i][3], xg3);
            }
        }

        for (int s = 0; s < Sn; ++s) {
            if (s) wait_group(g1, 32, (unsigned)s);

            const int p = s & 1;
            const int t = dir ? (Sn - 1 - s) : s;

            // critical: h loads (K=512 only) + dependent MFMAs
            unsigned hw[4][8];
            #pragma unroll
            for (int i = 0; i < 4; ++i)
                lda8(&h0_pk[(((size_t)p * 2 + dir) * Bn + bA) * Hn + (w * 4 + i) * 32 + ks * 8], hw[i]);

            f32x4 acc0 = xg0, acc1 = xg1, acc2 = xg2, acc3 = xg3;
            #pragma unroll
            for (int i = 0; i < 4; ++i) {
                short8 ah, al;
                unpack8(hw[i], ah, al);
                acc0 = mfma_bf16(ah, wh_h[i][0], acc0); acc0 = mfma_bf16(al, wh_h[i][0], acc0); acc0 = mfma_bf16(ah, wh_l[i][0], acc0);
                acc1 = mfma_bf16(ah, wh_h[i][1], acc1); acc1 = mfma_bf16(al, wh_h[i][1], acc1); acc1 = mfma_bf16(ah, wh_l[i][1], acc1);
                acc2 = mfma_bf16(ah, wh_h[i][2], acc2); acc2 = mfma_bf16(al, wh_h[i][2], acc2); acc2 = mfma_bf16(ah, wh_l[i][2], acc2);
                acc3 = mfma_bf16(ah, wh_h[i][3], acc3); acc3 = mfma_bf16(al, wh_h[i][3], acc3); acc3 = mfma_bf16(ah, wh_l[i][3], acc3);
            }
            *(f32x4*)&P[((w * 4 + 0) * 16 + lc) * 20 + ks * 4] = acc0;
            *(f32x4*)&P[((w * 4 + 1) * 16 + lc) * 20 + ks * 4] = acc1;
            *(f32x4*)&P[((w * 4 + 2) * 16 + lc) * 20 + ks * 4] = acc2;
            *(f32x4*)&P[((w * 4 + 3) * 16 + lc) * 20 + ks * 4] = acc3;
            __syncthreads();

            unsigned word;
            {
                float g4[4];
                #pragma unroll
                for (int gt = 0; gt < 4; ++gt) {
                    float sum = bias_r[gt];
                    #pragma unroll
                    for (int ww = 0; ww < 4; ++ww)
                        sum += P[((ww * 4 + gt) * 16 + (tid & 15)) * 20 + (tid >> 4)];
                    g4[gt] = sum;
                }
                const float ig = 1.f / (1.f + expf(-g4[0]));
                const float fg = 1.f / (1.f + expf(-g4[1]));
                const float gg = tanhf(g4[2]);
                const float og = 1.f / (1.f + expf(-g4[3]));
                c_reg = fg * c_reg + ig * gg;
                const float h = og * tanhf(c_reg);
                const ushort hhv = f2bf(h);
                const ushort hlv = f2bf(h - bf2f(hhv));
                word = (unsigned)hhv | ((unsigned)hlv << 16);
                sta32(&h0_pk[(((size_t)(p ^ 1) * 2 + dir) * Bn + cb) * Hn + ch], word);
            }
            // last step: out0 must be LLC-visible before publish(512) (phase-2 gate)
            if (s == Sn - 1)
                sta32(&out0_pk[((size_t)cb * Sn + t) * 1024 + dir * 512 + ch], word);

            publish_slot(&g1[hs], (unsigned)(s + 1));

            // hoisted off critical path: out0 store + next step's x-projection
            if (s < Sn - 1) {
                sta32(&out0_pk[((size_t)cb * Sn + t) * 1024 + dir * 512 + ch], word);
                const int tt = dir ? (Sn - 2 - s) : (s + 1);
                xg0 = {0.f,0.f,0.f,0.f}; xg1 = xg0; xg2 = xg0; xg3 = xg0;
                #pragma unroll
                for (int i = 0; i < 2; ++i) {
                    const int k0 = (w * 2 + i) * 32 + ks * 8;
                    short8 xh, xl;
                    split8(&x[((size_t)bA * Sn + tt) * Dn + k0], xh, xl);
                    xg0 = mfma_bf16(xh, wx_h[i][0], xg0); xg0 = mfma_bf16(xl, wx_h[i][0], xg0); xg0 = mfma_bf16(xh, wx_l[i][0], xg0);
                    xg1 = mfma_bf16(xh, wx_h[i][1], xg1); xg1 = mfma_bf16(xl, wx_h[i][1], xg1); xg1 = mfma_bf16(xh, wx_l[i][1], xg1);
                    xg2 = mfma_bf16(xh, wx_h[i][2], xg2); xg2 = mfma_bf16(xl, wx_h[i][2], xg2); xg2 = mfma_bf16(xh, wx_l[i][2], xg2);
                    xg3 = mfma_bf16(xh, wx_h[i][3], xg3); xg3 = mfma_bf16(xl, wx_h[i][3], xg3); xg3 = mfma_bf16(xh, wx_l[i][3], xg3);
                }
            }
        }
    }

    //==================== PHASE 2: layer 1 forward, 512 steps ====================
    {
        const int hs = (bid >> 2) & 63;    // hidden slice (8 hidden units)
        const int bt = bid & 3;
        unsigned* g2 = &flags[256 + bt * 64];   // P2 group: 64 consecutive words
        // x-part (out0, K=1024): 8 kg per wave
        short8 wx_h[8][2], wx_l[8][2];
        #pragma unroll
        for (int i = 0; i < 8; ++i) {
            const int k0 = (w * 8 + i) * 32 + ks * 8;
            #pragma unroll
            for (int nt = 0; nt < 2; ++nt) {
                const int c = nt * 16 + lc;
                const int r = (c >> 3) * 512 + hs * 8 + (c & 7);
                split8(&wih1f[(size_t)r * 1024 + k0], wx_h[i][nt], wx_l[i][nt]);
            }
        }
        // h-part (K=512): 4 kg per wave
        short8 wh_h[4][2], wh_l[4][2];
        #pragma unroll
        for (int i = 0; i < 4; ++i) {
            const int k0 = (w * 4 + i) * 32 + ks * 8;
            #pragma unroll
            for (int nt = 0; nt < 2; ++nt) {
                const int c = nt * 16 + lc;
                const int r = (c >> 3) * 512 + hs * 8 + (c & 7);
                split8(&whh1f[(size_t)r * 512 + k0], wh_h[i][nt], wh_l[i][nt]);
            }
        }
        const bool is_cell = (tid < 128);
        const int cb = bt * 16 + (tid >> 3);
        const int ch = hs * 8 + (tid & 7);
        float bias_r[4] = {0.f, 0.f, 0.f, 0.f};
        if (is_cell) {
            #pragma unroll
            for (int gt = 0; gt < 4; ++gt)
                bias_r[gt] = bih1f[gt * 512 + ch] + bhh1f[gt * 512 + ch];
        }
        float c_reg = 0.f;
        const int bA = bt * 16 + lc;

        // gate: both same-bt P1 groups (fwd & bwd) at epoch 512 -> out0 fully visible
        if (tid < 64)
            poll_ge(&flags[(tid >> 5) * 128 + bt * 32 + (tid & 31)], (unsigned)Sn);
        __syncthreads();

        // xg for step 0
        f32x4 xg0 = {0.f,0.f,0.f,0.f}, xg1 = xg0;
        {
            unsigned ow[8][8];
            #pragma unroll
            for (int i = 0; i < 8; ++i)
                lda8(&out0_pk[(size_t)bA * Sn * 1024 + (w * 8 + i) * 32 + ks * 8], ow[i]);
            #pragma unroll
            for (int i = 0; i < 8; ++i) {
                short8 ah, al;
                unpack8(ow[i], ah, al);
                xg0 = mfma_bf16(ah, wx_h[i][0], xg0); xg0 = mfma_bf16(al, wx_h[i][0], xg0); xg0 = mfma_bf16(ah, wx_l[i][0], xg0);
                xg1 = mfma_bf16(ah, wx_h[i][1], xg1); xg1 = mfma_bf16(al, wx_h[i][1], xg1); xg1 = mfma_bf16(ah, wx_l[i][1], xg1);
            }
        }

        for (int s = 0; s < Sn; ++s) {
            if (s) wait_group(g2, 64, (unsigned)s);

            const int p = s & 1;
            // critical: h1 loads (K=512) + dependent MFMAs
            unsigned hw[4][8];
            #pragma unroll
            for (int i = 0; i < 4; ++i)
                lda8(&h1_pk[((size_t)p * Bn + bA) * Hn + (w * 4 + i) * 32 + ks * 8], hw[i]);

            f32x4 acc0 = xg0, acc1 = xg1;
            #pragma unroll
            for (int i = 0; i < 4; ++i) {
                short8 ah, al;
                unpack8(hw[i], ah, al);
                acc0 = mfma_bf16(ah, wh_h[i][0], acc0); acc0 = mfma_bf16(al, wh_h[i][0], acc0); acc0 = mfma_bf16(ah, wh_l[i][0], acc0);
                acc1 = mfma_bf16(ah, wh_h[i][1], acc1); acc1 = mfma_bf16(al, wh_h[i][1], acc1); acc1 = mfma_bf16(ah, wh_l[i][1], acc1);
            }
            *(f32x4*)&P[((w * 2 + 0) * 16 + lc) * 20 + ks * 4] = acc0;
            *(f32x4*)&P[((w * 2 + 1) * 16 + lc) * 20 + ks * 4] = acc1;
            __syncthreads();

            if (is_cell) {
                float g4[4];
                #pragma unroll
                for (int gt = 0; gt < 4; ++gt) {
                    const int cc = gt * 8 + (tid & 7);
                    const int nt = cc >> 4, g = cc & 15;
                    float sum = bias_r[gt];
                    #pragma unroll
                    for (int ww = 0; ww < 4; ++ww)
                        sum += P[((ww * 2 + nt) * 16 + g) * 20 + (tid >> 3)];
                    g4[gt] = sum;
                }
                const float ig = 1.f / (1.f + expf(-g4[0]));
                const float fg = 1.f / (1.f + expf(-g4[1]));
                const float gg = tanhf(g4[2]);
                const float og = 1.f / (1.f + expf(-g4[3]));
                c_reg = fg * c_reg + ig * gg;
                const float h = og * tanhf(c_reg);
                const ushort hhv = f2bf(h);
                const ushort hlv = f2bf(h - bf2f(hhv));
                const unsigned word = (unsigned)hhv | ((unsigned)hlv << 16);
                sta32(&h1_pk[((size_t)(p ^ 1) * Bn + cb) * Hn + ch], word);
            }
            publish_slot(&g2[bid >> 2], (unsigned)(s + 1));

            // hoisted: next step's out0 projection
            if (s < Sn - 1) {
                unsigned ow[8][8];
                #pragma unroll
                for (int i = 0; i < 8; ++i)
                    lda8(&out0_pk[((size_t)bA * Sn + (s + 1)) * 1024 + (w * 8 + i) * 32 + ks * 8], ow[i]);
                xg0 = {0.f,0.f,0.f,0.f}; xg1 = xg0;
                #pragma unroll
                for (int i = 0; i < 8; ++i) {
                    short8 ah, al;
                    unpack8(ow[i], ah, al);
                    xg0 = mfma_bf16(ah, wx_h[i][0], xg0); xg0 = mfma_bf16(al, wx_h[i][0], xg0); xg0 = mfma_bf16(ah, wx_l[i][0], xg0);
                    xg1 = mfma_bf16(ah, wx_h[i][1], xg1); xg1 = mfma_bf16(al, wx_h[i][1], xg1); xg1 = mfma_bf16(ah, wx_l[i][1], xg1);
                }
            }
        }
    }

    //==================== PHASE 3: layer 1 backward, first step only (t = S-1) ====================
    {
        const int hs = (bid >> 2) & 63;
        const int bt = bid & 3;
        const int bA = bt * 16 + lc;
        const int t = Sn - 1;
        unsigned hw[8][8];
        #pragma unroll
        for (int i = 0; i < 8; ++i) {
            const int k0 = (w * 8 + i) * 32 + ks * 8;
            lda8(&out0_pk[((size_t)bA * Sn + t) * 1024 + k0], hw[i]);
        }
        f32x4 acc0 = {0.f,0.f,0.f,0.f}, acc1 = acc0;
        #pragma unroll
        for (int i = 0; i < 8; ++i) {
            const int k0 = (w * 8 + i) * 32 + ks * 8;
            short8 ah, al;
            unpack8(hw[i], ah, al);
            #pragma unroll
            for (int nt = 0; nt < 2; ++nt) {
                const int c = nt * 16 + lc;
                const int r = (c >> 3) * 512 + hs * 8 + (c & 7);
                short8 bh, bl;
                split8(&wih1b[(size_t)r * 1024 + k0], bh, bl);
                f32x4 a = (nt == 0) ? acc0 : acc1;
                a = mfma_bf16(ah, bh, a);
                a = mfma_bf16(al, bh, a);
                a = mfma_bf16(ah, bl, a);
                if (nt == 0) acc0 = a; else acc1 = a;
            }
        }
        *(f32x4*)&P[((w * 2 + 0) * 16 + lc) * 20 + ks * 4] = acc0;
        *(f32x4*)&P[((w * 2 + 1) * 16 + lc) * 20 + ks * 4] = acc1;
        __syncthreads();
        if (tid < 128) {
            const int cb = bt * 16 + (tid >> 3);
            const int ch = hs * 8 + (tid & 7);
            float g4[4];
            #pragma unroll
            for (int gt = 0; gt < 4; ++gt) {
                const int cc = gt * 8 + (tid & 7);
                const int nt = cc >> 4, g = cc & 15;
                float sum = bih1b[gt * 512 + ch] + bhh1b[gt * 512 + ch];
                #pragma unroll
                for (int ww = 0; ww < 4; ++ww)
                    sum += P[((ww * 2 + nt) * 16 + g) * 20 + (tid >> 3)];
                g4[gt] = sum;
            }
            const float ig = 1.f / (1.f + expf(-g4[0]));
            const float gg = tanhf(g4[2]);
            const float og = 1.f / (1.f + expf(-g4[3]));
            const float c = ig * gg;           // c_prev = 0
            const float h = og * tanhf(c);
            const ushort hhv = f2bf(h);
            const ushort hlv = f2bf(h - bf2f(hhv));
            sta32(&h1b_pk[(size_t)cb * Hn + ch], (unsigned)hhv | ((unsigned)hlv << 16));
        }
        publish_slot(&flags[512 + bid], 1u);
    }

    //==================== PHASE 4: FC (blocks 0..63, after global wait) ====================
    if (bid < Bn) {
        if (tid < 256) poll_ge(&flags[512 + tid], 1u);
        __syncthreads();
        {
            // final forward h (parity after 512 steps is parity 0) + backward-first h
            const unsigned long long* qf =
                (const unsigned long long*)&h1_pk[(size_t)0 * Bn * Hn + (size_t)bid * Hn];
            const unsigned long long* qb =
                (const unsigned long long*)&h1b_pk[(size_t)bid * Hn];
            unsigned long long vf = __hip_atomic_load(qf + tid, __ATOMIC_RELAXED, __HIP_MEMORY_SCOPE_AGENT);
            unsigned long long vb = __hip_atomic_load(qb + tid, __ATOMIC_RELAXED, __HIP_MEMORY_SCOPE_AGENT);
            const int j = tid * 2;
            hstage[0][j]     = bf2f((ushort)(vf & 0xffff))         + bf2f((ushort)((vf >> 16) & 0xffff));
            hstage[0][j + 1] = bf2f((ushort)((vf >> 32) & 0xffff)) + bf2f((ushort)((vf >> 48) & 0xffff));
            hstage[1][j]     = bf2f((ushort)(vb & 0xffff))         + bf2f((ushort)((vb >> 16) & 0xffff));
            hstage[1][j + 1] = bf2f((ushort)((vb >> 32) & 0xffff)) + bf2f((ushort)((vb >> 48) & 0xffff));
        }
        __syncthreads();
        if (tid < On) {
            const int b = bid, o = tid;
            float sum = fcb[o];
            const float* wrow = &fcw[(size_t)o * 1024];
            #pragma unroll 4
            for (int j = 0; j < Hn; ++j) sum += hstage[0][j] * wrow[j];
            #pragma unroll 4
            for (int j = 0; j < Hn; ++j) sum += hstage[1][j] * wrow[512 + j];
            out[(size_t)b * On + o] = sum;
        }
    }
}

extern "C" void kernel_launch(void* const* d_in, const int* in_sizes, int n_in,
                              void* d_out, int out_size, void* d_ws, size_t ws_size,
                              hipStream_t stream)
{
    const float* x     = (const float*)d_in[0];
    const float* wih0f = (const float*)d_in[1];
    const float* whh0f = (const float*)d_in[2];
    const float* bih0f = (const float*)d_in[3];
    const float* bhh0f = (const float*)d_in[4];
    const float* wih0b = (const float*)d_in[5];
    const float* whh0b = (const float*)d_in[6];
    const float* bih0b = (const float*)d_in[7];
    const float* bhh0b = (const float*)d_in[8];
    const float* wih1f = (const float*)d_in[9];
    const float* whh1f = (const float*)d_in[10];
    const float* bih1f = (const float*)d_in[11];
    const float* bhh1f = (const float*)d_in[12];
    const float* wih1b = (const float*)d_in[13];
    const float* whh1b = (const float*)d_in[14];
    const float* bih1b = (const float*)d_in[15];
    const float* bhh1b = (const float*)d_in[16];
    const float* fcw   = (const float*)d_in[17];
    const float* fcb   = (const float*)d_in[18];

    char* ws = (char*)d_ws;
    size_t off = 0;
    unsigned* flags  = (unsigned*)(ws + off); off += (size_t)768 * 4;     // P1/P2/P3 packed
    unsigned* h0_pk  = (unsigned*)(ws + off); off += (size_t)2 * 2 * Bn * Hn * 4;
    unsigned* h1_pk  = (unsigned*)(ws + off); off += (size_t)2 * Bn * Hn * 4;
    size_t zero_end = off;                    // flags + recurrent h state must start zeroed
    unsigned* h1b_pk = (unsigned*)(ws + off); off += (size_t)Bn * Hn * 4;
    unsigned* out0_pk = (unsigned*)(ws + off); off += (size_t)Bn * Sn * 2 * Hn * 4;

    hipMemsetAsync(d_ws, 0, zero_end, stream);

    hipLaunchKernelGGL(bilstm_persistent, dim3(256), dim3(256), 0, stream,
        x, wih0f, whh0f, bih0f, bhh0f, wih0b, whh0b, bih0b, bhh0b,
        wih1f, whh1f, bih1f, bhh1f, wih1b, whh1b, bih1b, bhh1b,
        fcw, fcb,
        flags, h0_pk, h1_pk, h1b_pk, out0_pk,
        (float*)d_out);
}

// Round 9
// 6160.183 us; speedup vs baseline: 6.9770x; 1.0707x over previous
//
#include <hip/hip_runtime.h>
#include <math.h>

#define Bn 64
#define Sn 512
#define Dn 256
#define Hn 512
#define On 128

using short8 = __attribute__((ext_vector_type(8))) short;
using f32x4  = __attribute__((ext_vector_type(4))) float;

union U8 { unsigned u[4]; short8 s; };

__device__ __forceinline__ ushort f2bf(float f) {
    unsigned u = __float_as_uint(f);
    u = u + 0x7FFFu + ((u >> 16) & 1u);   // round-to-nearest-even
    return (ushort)(u >> 16);
}
__device__ __forceinline__ float bf2f(ushort b) {
    return __uint_as_float(((unsigned)b) << 16);
}
// split 8 consecutive fp32 into hi/lo bf16 fragments
__device__ __forceinline__ void split8(const float* __restrict__ p, short8& hi, short8& lo) {
    #pragma unroll
    for (int j = 0; j < 8; ++j) {
        float w = p[j];
        ushort h = f2bf(w);
        hi[j] = (short)h;
        lo[j] = (short)f2bf(w - bf2f(h));
    }
}
// opaque register pin: compiler cannot rematerialize past this (rule: asm def is opaque)
__device__ __forceinline__ void pin8(short8& v) { asm volatile("" : "+v"(v)); }

// ---- LLC-coherent data access via relaxed agent atomics (proven R6-R8) ----
__device__ __forceinline__ void lda8(const unsigned* p, unsigned* w) {
    const unsigned long long* q = (const unsigned long long*)p;
    #pragma unroll
    for (int j = 0; j < 4; ++j) {
        unsigned long long v = __hip_atomic_load(q + j, __ATOMIC_RELAXED, __HIP_MEMORY_SCOPE_AGENT);
        w[2*j]   = (unsigned)v;
        w[2*j+1] = (unsigned)(v >> 32);
    }
}
__device__ __forceinline__ void unpack8(const unsigned* w, short8& hi8, short8& lo8) {
    U8 a, b;
    #pragma unroll
    for (int j = 0; j < 4; ++j) {
        a.u[j] = (w[2*j] & 0xffffu) | (w[2*j+1] << 16);
        b.u[j] = (w[2*j] >> 16)     | (w[2*j+1] & 0xffff0000u);
    }
    hi8 = a.s; lo8 = b.s;
}
__device__ __forceinline__ void sta32(unsigned* p, unsigned v) {
    __hip_atomic_store(p, v, __ATOMIC_RELAXED, __HIP_MEMORY_SCOPE_AGENT);
}

// ---- packed-flag sync fabric (R8) ----
__device__ __forceinline__ void poll_ge(const unsigned* p, unsigned epoch) {
    while (__hip_atomic_load(p, __ATOMIC_RELAXED, __HIP_MEMORY_SCOPE_AGENT) < epoch)
        __builtin_amdgcn_s_sleep(1);
}
__device__ __forceinline__ void wait_group(const unsigned* base, int n, unsigned epoch) {
    if ((int)threadIdx.x < n)
        poll_ge(base + threadIdx.x, epoch);
    __syncthreads();
}
__device__ __forceinline__ void publish_slot(unsigned* slot, unsigned epoch) {
    __syncthreads();
    if (threadIdx.x == 0)
        __hip_atomic_store(slot, epoch, __ATOMIC_RELAXED, __HIP_MEMORY_SCOPE_AGENT);
}

__device__ __forceinline__ f32x4 mfma_bf16(short8 a, short8 b, f32x4 c) {
    return __builtin_amdgcn_mfma_f32_16x16x32_bf16(a, b, c, 0, 0, 0);
}

__global__ __launch_bounds__(256, 1) void bilstm_persistent(
    const float* __restrict__ x,
    const float* __restrict__ wih0f, const float* __restrict__ whh0f,
    const float* __restrict__ bih0f, const float* __restrict__ bhh0f,
    const float* __restrict__ wih0b, const float* __restrict__ whh0b,
    const float* __restrict__ bih0b, const float* __restrict__ bhh0b,
    const float* __restrict__ wih1f, const float* __restrict__ whh1f,
    const float* __restrict__ bih1f, const float* __restrict__ bhh1f,
    const float* __restrict__ wih1b, const float* __restrict__ whh1b,
    const float* __restrict__ bih1b, const float* __restrict__ bhh1b,
    const float* __restrict__ fcw,  const float* __restrict__ fcb,
    unsigned* flags,     // [0..256) P1 per-step, [256..512) P2 per-step, [512..768) P3 done
    unsigned* h0_pk,     // [2 parity][2 dir][B][H] packed (hi | lo<<16)
    unsigned* h1_pk,     // [2 parity][B][H] packed
    unsigned* h1b_pk,    // [B][H] packed
    unsigned* out0_pk,   // [B][S][2H] packed
    float* out)
{
    const int bid = blockIdx.x;
    const int tid = threadIdx.x;
    const int l  = tid & 63;    // lane
    const int w  = tid >> 6;    // wave 0..3 (K-split)
    const int lc = l & 15;      // col lane (gate col) / A-row lane (batch)
    const int ks = l >> 4;      // k-segment 0..3 within a 32-k block

    __shared__ float P[4 * 4 * 16 * 20];   // 20KB: [wave][ntile][gatecol][batch+pad]
    __shared__ short8 wl[6144];            // 96KB: per-lane weight-lo/x closet
    __shared__ float hstage[2][Hn];        // 4KB: FC staging

    //==================== PHASE 1: layer 0, both dirs, 512 steps ====================
    {
        const int dir = bid >> 7;          // 0..127 fwd, 128..255 bwd
        const int hs  = (bid >> 2) & 31;   // hidden slice (16 hidden units)
        const int bt  = bid & 3;           // batch tile (16 batches)
        unsigned* g1 = &flags[(dir * 4 + bt) * 32];
        const float* wih = dir ? wih0b : wih0f;
        const float* whh = dir ? whh0b : whh0f;
        const float* bih = dir ? bih0b : bih0f;
        const float* bhh = dir ? bhh0b : bhh0f;

        // ---- stage weights ONCE: hi -> pinned VGPR, lo -> per-lane LDS slots ----
        short8 wh_hi[4][4];                 // h-part hi (critical path), 64 VGPR
        #pragma unroll
        for (int i = 0; i < 4; ++i) {
            const int k0 = (w * 4 + i) * 32 + ks * 8;
            #pragma unroll
            for (int nt = 0; nt < 4; ++nt) {
                const int r = nt * 512 + hs * 16 + lc;
                short8 hi, lo;
                split8(&whh[(size_t)r * 512 + k0], hi, lo);
                wh_hi[i][nt] = hi;
                wl[(w * 16 + i * 4 + nt) * 64 + l] = lo;
            }
        }
        short8 wx_hi[2][4];                 // x-part hi, 32 VGPR
        #pragma unroll
        for (int i = 0; i < 2; ++i) {
            const int k0 = (w * 2 + i) * 32 + ks * 8;
            #pragma unroll
            for (int nt = 0; nt < 4; ++nt) {
                const int r = nt * 512 + hs * 16 + lc;
                short8 hi, lo;
                split8(&wih[(size_t)r * 256 + k0], hi, lo);
                wx_hi[i][nt] = hi;
                wl[4096 + (w * 8 + i * 4 + nt) * 64 + l] = lo;
            }
        }
        #pragma unroll
        for (int i = 0; i < 4; ++i)
            #pragma unroll
            for (int nt = 0; nt < 4; ++nt) pin8(wh_hi[i][nt]);
        #pragma unroll
        for (int i = 0; i < 2; ++i)
            #pragma unroll
            for (int nt = 0; nt < 4; ++nt) pin8(wx_hi[i][nt]);
        const short8* whlo = &wl[(w * 16) * 64 + l];          // + (i*4+nt)*64
        const short8* wxlo = &wl[4096 + (w * 8) * 64 + l];    // + (i*4+nt)*64

        const int cb = bt * 16 + (tid >> 4);
        const int ch = hs * 16 + (tid & 15);
        float bias_r[4];
        #pragma unroll
        for (int gt = 0; gt < 4; ++gt)
            bias_r[gt] = bih[gt * 512 + ch] + bhh[gt * 512 + ch];
        float c_reg = 0.f;
        const int bA = bt * 16 + lc;       // A-operand batch row

        // xg for step 0
        f32x4 xg0 = {0.f,0.f,0.f,0.f}, xg1 = xg0, xg2 = xg0, xg3 = xg0;
        {
            const int tt = dir ? (Sn - 1) : 0;
            #pragma unroll
            for (int i = 0; i < 2; ++i) {
                const int k0 = (w * 2 + i) * 32 + ks * 8;
                short8 xh, xl;
                split8(&x[((size_t)bA * Sn + tt) * Dn + k0], xh, xl);
                xg0 = mfma_bf16(xh, wx_hi[i][0], xg0); xg0 = mfma_bf16(xl, wx_hi[i][0], xg0); xg0 = mfma_bf16(xh, wxlo[(i*4+0)*64], xg0);
                xg1 = mfma_bf16(xh, wx_hi[i][1], xg1); xg1 = mfma_bf16(xl, wx_hi[i][1], xg1); xg1 = mfma_bf16(xh, wxlo[(i*4+1)*64], xg1);
                xg2 = mfma_bf16(xh, wx_hi[i][2], xg2); xg2 = mfma_bf16(xl, wx_hi[i][2], xg2); xg2 = mfma_bf16(xh, wxlo[(i*4+2)*64], xg2);
                xg3 = mfma_bf16(xh, wx_hi[i][3], xg3); xg3 = mfma_bf16(xl, wx_hi[i][3], xg3); xg3 = mfma_bf16(xh, wxlo[(i*4+3)*64], xg3);
            }
        }

        for (int s = 0; s < Sn; ++s) {
            if (s) wait_group(g1, 32, (unsigned)s);

            const int p = s & 1;
            const int t = dir ? (Sn - 1 - s) : s;

            // critical: h loads (K=512 only) + dependent MFMAs (B-ops: pinned regs + LDS)
            unsigned hw[4][8];
            #pragma unroll
            for (int i = 0; i < 4; ++i)
                lda8(&h0_pk[(((size_t)p * 2 + dir) * Bn + bA) * Hn + (w * 4 + i) * 32 + ks * 8], hw[i]);

            f32x4 acc0 = xg0, acc1 = xg1, acc2 = xg2, acc3 = xg3;
            #pragma unroll
            for (int i = 0; i < 4; ++i) {
                short8 ah, al;
                unpack8(hw[i], ah, al);
                acc0 = mfma_bf16(ah, wh_hi[i][0], acc0); acc0 = mfma_bf16(al, wh_hi[i][0], acc0); acc0 = mfma_bf16(ah, whlo[(i*4+0)*64], acc0);
                acc1 = mfma_bf16(ah, wh_hi[i][1], acc1); acc1 = mfma_bf16(al, wh_hi[i][1], acc1); acc1 = mfma_bf16(ah, whlo[(i*4+1)*64], acc1);
                acc2 = mfma_bf16(ah, wh_hi[i][2], acc2); acc2 = mfma_bf16(al, wh_hi[i][2], acc2); acc2 = mfma_bf16(ah, whlo[(i*4+2)*64], acc2);
                acc3 = mfma_bf16(ah, wh_hi[i][3], acc3); acc3 = mfma_bf16(al, wh_hi[i][3], acc3); acc3 = mfma_bf16(ah, whlo[(i*4+3)*64], acc3);
            }
            *(f32x4*)&P[((w * 4 + 0) * 16 + lc) * 20 + ks * 4] = acc0;
            *(f32x4*)&P[((w * 4 + 1) * 16 + lc) * 20 + ks * 4] = acc1;
            *(f32x4*)&P[((w * 4 + 2) * 16 + lc) * 20 + ks * 4] = acc2;
            *(f32x4*)&P[((w * 4 + 3) * 16 + lc) * 20 + ks * 4] = acc3;
            __syncthreads();

            unsigned word;
            {
                float g4[4];
                #pragma unroll
                for (int gt = 0; gt < 4; ++gt) {
                    float sum = bias_r[gt];
                    #pragma unroll
                    for (int ww = 0; ww < 4; ++ww)
                        sum += P[((ww * 4 + gt) * 16 + (tid & 15)) * 20 + (tid >> 4)];
                    g4[gt] = sum;
                }
                const float ig = 1.f / (1.f + expf(-g4[0]));
                const float fg = 1.f / (1.f + expf(-g4[1]));
                const float gg = tanhf(g4[2]);
                const float og = 1.f / (1.f + expf(-g4[3]));
                c_reg = fg * c_reg + ig * gg;
                const float h = og * tanhf(c_reg);
                const ushort hhv = f2bf(h);
                const ushort hlv = f2bf(h - bf2f(hhv));
                word = (unsigned)hhv | ((unsigned)hlv << 16);
                sta32(&h0_pk[(((size_t)(p ^ 1) * 2 + dir) * Bn + cb) * Hn + ch], word);
            }
            if (s == Sn - 1)
                sta32(&out0_pk[((size_t)cb * Sn + t) * 1024 + dir * 512 + ch], word);

            publish_slot(&g1[hs], (unsigned)(s + 1));

            // hoisted off critical path: out0 store + next step's x-projection
            if (s < Sn - 1) {
                sta32(&out0_pk[((size_t)cb * Sn + t) * 1024 + dir * 512 + ch], word);
                const int tt = dir ? (Sn - 2 - s) : (s + 1);
                xg0 = {0.f,0.f,0.f,0.f}; xg1 = xg0; xg2 = xg0; xg3 = xg0;
                #pragma unroll
                for (int i = 0; i < 2; ++i) {
                    const int k0 = (w * 2 + i) * 32 + ks * 8;
                    short8 xh, xl;
                    split8(&x[((size_t)bA * Sn + tt) * Dn + k0], xh, xl);
                    xg0 = mfma_bf16(xh, wx_hi[i][0], xg0); xg0 = mfma_bf16(xl, wx_hi[i][0], xg0); xg0 = mfma_bf16(xh, wxlo[(i*4+0)*64], xg0);
                    xg1 = mfma_bf16(xh, wx_hi[i][1], xg1); xg1 = mfma_bf16(xl, wx_hi[i][1], xg1); xg1 = mfma_bf16(xh, wxlo[(i*4+1)*64], xg1);
                    xg2 = mfma_bf16(xh, wx_hi[i][2], xg2); xg2 = mfma_bf16(xl, wx_hi[i][2], xg2); xg2 = mfma_bf16(xh, wxlo[(i*4+2)*64], xg2);
                    xg3 = mfma_bf16(xh, wx_hi[i][3], xg3); xg3 = mfma_bf16(xl, wx_hi[i][3], xg3); xg3 = mfma_bf16(xh, wxlo[(i*4+3)*64], xg3);
                }
            }
        }
    }

    //==================== PHASE 2: layer 1 forward, 512 steps ====================
    {
        const int hs = (bid >> 2) & 63;    // hidden slice (8 hidden units)
        const int bt = bid & 3;
        unsigned* g2 = &flags[256 + bt * 64];

        // ---- stage weights ONCE (reuse wl; phase-1 reads all done: last publish barrier) ----
        short8 wh_hi2[4][2];               // 32 VGPR
        #pragma unroll
        for (int i = 0; i < 4; ++i) {
            const int k0 = (w * 4 + i) * 32 + ks * 8;
            #pragma unroll
            for (int nt = 0; nt < 2; ++nt) {
                const int c = nt * 16 + lc;
                const int r = (c >> 3) * 512 + hs * 8 + (c & 7);
                short8 hi, lo;
                split8(&whh1f[(size_t)r * 512 + k0], hi, lo);
                wh_hi2[i][nt] = hi;
                wl[(w * 8 + i * 2 + nt) * 64 + l] = lo;
            }
        }
        short8 wx_hi2[8][2];               // 64 VGPR
        #pragma unroll
        for (int i = 0; i < 8; ++i) {
            const int k0 = (w * 8 + i) * 32 + ks * 8;
            #pragma unroll
            for (int nt = 0; nt < 2; ++nt) {
                const int c = nt * 16 + lc;
                const int r = (c >> 3) * 512 + hs * 8 + (c & 7);
                short8 hi, lo;
                split8(&wih1f[(size_t)r * 1024 + k0], hi, lo);
                wx_hi2[i][nt] = hi;
                wl[2048 + (w * 16 + i * 2 + nt) * 64 + l] = lo;
            }
        }
        #pragma unroll
        for (int i = 0; i < 4; ++i)
            #pragma unroll
            for (int nt = 0; nt < 2; ++nt) pin8(wh_hi2[i][nt]);
        #pragma unroll
        for (int i = 0; i < 8; ++i)
            #pragma unroll
            for (int nt = 0; nt < 2; ++nt) pin8(wx_hi2[i][nt]);
        const short8* whlo2 = &wl[(w * 8) * 64 + l];            // + (i*2+nt)*64
        const short8* wxlo2 = &wl[2048 + (w * 16) * 64 + l];    // + (i*2+nt)*64

        const bool is_cell = (tid < 128);
        const int cb = bt * 16 + (tid >> 3);
        const int ch = hs * 8 + (tid & 7);
        float bias_r[4] = {0.f, 0.f, 0.f, 0.f};
        if (is_cell) {
            #pragma unroll
            for (int gt = 0; gt < 4; ++gt)
                bias_r[gt] = bih1f[gt * 512 + ch] + bhh1f[gt * 512 + ch];
        }
        float c_reg = 0.f;
        const int bA = bt * 16 + lc;

        // gate: both same-bt P1 groups at epoch 512 -> out0 fully visible
        if (tid < 64)
            poll_ge(&flags[(tid >> 5) * 128 + bt * 32 + (tid & 31)], (unsigned)Sn);
        __syncthreads();

        // xg for step 0
        f32x4 xg0 = {0.f,0.f,0.f,0.f}, xg1 = xg0;
        {
            unsigned ow[8][8];
            #pragma unroll
            for (int i = 0; i < 8; ++i)
                lda8(&out0_pk[(size_t)bA * Sn * 1024 + (w * 8 + i) * 32 + ks * 8], ow[i]);
            #pragma unroll
            for (int i = 0; i < 8; ++i) {
                short8 ah, al;
                unpack8(ow[i], ah, al);
                xg0 = mfma_bf16(ah, wx_hi2[i][0], xg0); xg0 = mfma_bf16(al, wx_hi2[i][0], xg0); xg0 = mfma_bf16(ah, wxlo2[(i*2+0)*64], xg0);
                xg1 = mfma_bf16(ah, wx_hi2[i][1], xg1); xg1 = mfma_bf16(al, wx_hi2[i][1], xg1); xg1 = mfma_bf16(ah, wxlo2[(i*2+1)*64], xg1);
            }
        }

        for (int s = 0; s < Sn; ++s) {
            if (s) wait_group(g2, 64, (unsigned)s);

            const int p = s & 1;
            unsigned hw[4][8];
            #pragma unroll
            for (int i = 0; i < 4; ++i)
                lda8(&h1_pk[((size_t)p * Bn + bA) * Hn + (w * 4 + i) * 32 + ks * 8], hw[i]);

            f32x4 acc0 = xg0, acc1 = xg1;
            #pragma unroll
            for (int i = 0; i < 4; ++i) {
                short8 ah, al;
                unpack8(hw[i], ah, al);
                acc0 = mfma_bf16(ah, wh_hi2[i][0], acc0); acc0 = mfma_bf16(al, wh_hi2[i][0], acc0); acc0 = mfma_bf16(ah, whlo2[(i*2+0)*64], acc0);
                acc1 = mfma_bf16(ah, wh_hi2[i][1], acc1); acc1 = mfma_bf16(al, wh_hi2[i][1], acc1); acc1 = mfma_bf16(ah, whlo2[(i*2+1)*64], acc1);
            }
            *(f32x4*)&P[((w * 2 + 0) * 16 + lc) * 20 + ks * 4] = acc0;
            *(f32x4*)&P[((w * 2 + 1) * 16 + lc) * 20 + ks * 4] = acc1;
            __syncthreads();

            if (is_cell) {
                float g4[4];
                #pragma unroll
                for (int gt = 0; gt < 4; ++gt) {
                    const int cc = gt * 8 + (tid & 7);
                    const int nt = cc >> 4, g = cc & 15;
                    float sum = bias_r[gt];
                    #pragma unroll
                    for (int ww = 0; ww < 4; ++ww)
                        sum += P[((ww * 2 + nt) * 16 + g) * 20 + (tid >> 3)];
                    g4[gt] = sum;
                }
                const float ig = 1.f / (1.f + expf(-g4[0]));
                const float fg = 1.f / (1.f + expf(-g4[1]));
                const float gg = tanhf(g4[2]);
                const float og = 1.f / (1.f + expf(-g4[3]));
                c_reg = fg * c_reg + ig * gg;
                const float h = og * tanhf(c_reg);
                const ushort hhv = f2bf(h);
                const ushort hlv = f2bf(h - bf2f(hhv));
                const unsigned word = (unsigned)hhv | ((unsigned)hlv << 16);
                sta32(&h1_pk[((size_t)(p ^ 1) * Bn + cb) * Hn + ch], word);
            }
            publish_slot(&g2[bid >> 2], (unsigned)(s + 1));

            // hoisted: next step's out0 projection
            if (s < Sn - 1) {
                unsigned ow[8][8];
                #pragma unroll
                for (int i = 0; i < 8; ++i)
                    lda8(&out0_pk[((size_t)bA * Sn + (s + 1)) * 1024 + (w * 8 + i) * 32 + ks * 8], ow[i]);
                xg0 = {0.f,0.f,0.f,0.f}; xg1 = xg0;
                #pragma unroll
                for (int i = 0; i < 8; ++i) {
                    short8 ah, al;
                    unpack8(ow[i], ah, al);
                    xg0 = mfma_bf16(ah, wx_hi2[i][0], xg0); xg0 = mfma_bf16(al, wx_hi2[i][0], xg0); xg0 = mfma_bf16(ah, wxlo2[(i*2+0)*64], xg0);
                    xg1 = mfma_bf16(ah, wx_hi2[i][1], xg1); xg1 = mfma_bf16(al, wx_hi2[i][1], xg1); xg1 = mfma_bf16(ah, wxlo2[(i*2+1)*64], xg1);
                }
            }
        }
    }

    //==================== PHASE 3: layer 1 backward, first step only (t = S-1) ====================
    {
        const int hs = (bid >> 2) & 63;
        const int bt = bid & 3;
        const int bA = bt * 16 + lc;
        const int t = Sn - 1;
        unsigned hw[8][8];
        #pragma unroll
        for (int i = 0; i < 8; ++i) {
            const int k0 = (w * 8 + i) * 32 + ks * 8;
            lda8(&out0_pk[((size_t)bA * Sn + t) * 1024 + k0], hw[i]);
        }
        f32x4 acc0 = {0.f,0.f,0.f,0.f}, acc1 = acc0;
        #pragma unroll
        for (int i = 0; i < 8; ++i) {
            const int k0 = (w * 8 + i) * 32 + ks * 8;
            short8 ah, al;
            unpack8(hw[i], ah, al);
            #pragma unroll
            for (int nt = 0; nt < 2; ++nt) {
                const int c = nt * 16 + lc;
                const int r = (c >> 3) * 512 + hs * 8 + (c & 7);
                short8 bh, bl;
                split8(&wih1b[(size_t)r * 1024 + k0], bh, bl);
                f32x4 a = (nt == 0) ? acc0 : acc1;
                a = mfma_bf16(ah, bh, a);
                a = mfma_bf16(al, bh, a);
                a = mfma_bf16(ah, bl, a);
                if (nt == 0) acc0 = a; else acc1 = a;
            }
        }
        *(f32x4*)&P[((w * 2 + 0) * 16 + lc) * 20 + ks * 4] = acc0;
        *(f32x4*)&P[((w * 2 + 1) * 16 + lc) * 20 + ks * 4] = acc1;
        __syncthreads();
        if (tid < 128) {
            const int cb = bt * 16 + (tid >> 3);
            const int ch = hs * 8 + (tid & 7);
            float g4[4];
            #pragma unroll
            for (int gt = 0; gt < 4; ++gt) {
                const int cc = gt * 8 + (tid & 7);
                const int nt = cc >> 4, g = cc & 15;
                float sum = bih1b[gt * 512 + ch] + bhh1b[gt * 512 + ch];
                #pragma unroll
                for (int ww = 0; ww < 4; ++ww)
                    sum += P[((ww * 2 + nt) * 16 + g) * 20 + (tid >> 3)];
                g4[gt] = sum;
            }
            const float ig = 1.f / (1.f + expf(-g4[0]));
            const float gg = tanhf(g4[2]);
            const float og = 1.f / (1.f + expf(-g4[3]));
            const float c = ig * gg;           // c_prev = 0
            const float h = og * tanhf(c);
            const ushort hhv = f2bf(h);
            const ushort hlv = f2bf(h - bf2f(hhv));
            sta32(&h1b_pk[(size_t)cb * Hn + ch], (unsigned)hhv | ((unsigned)hlv << 16));
        }
        publish_slot(&flags[512 + bid], 1u);
    }

    //==================== PHASE 4: FC (blocks 0..63, after global wait) ====================
    if (bid < Bn) {
        if (tid < 256) poll_ge(&flags[512 + tid], 1u);
        __syncthreads();
        {
            const unsigned long long* qf =
                (const unsigned long long*)&h1_pk[(size_t)0 * Bn * Hn + (size_t)bid * Hn];
            const unsigned long long* qb =
                (const unsigned long long*)&h1b_pk[(size_t)bid * Hn];
            unsigned long long vf = __hip_atomic_load(qf + tid, __ATOMIC_RELAXED, __HIP_MEMORY_SCOPE_AGENT);
            unsigned long long vb = __hip_atomic_load(qb + tid, __ATOMIC_RELAXED, __HIP_MEMORY_SCOPE_AGENT);
            const int j = tid * 2;
            hstage[0][j]     = bf2f((ushort)(vf & 0xffff))         + bf2f((ushort)((vf >> 16) & 0xffff));
            hstage[0][j + 1] = bf2f((ushort)((vf >> 32) & 0xffff)) + bf2f((ushort)((vf >> 48) & 0xffff));
            hstage[1][j]     = bf2f((ushort)(vb & 0xffff))         + bf2f((ushort)((vb >> 16) & 0xffff));
            hstage[1][j + 1] = bf2f((ushort)((vb >> 32) & 0xffff)) + bf2f((ushort)((vb >> 48) & 0xffff));
        }
        __syncthreads();
        if (tid < On) {
            const int b = bid, o = tid;
            float sum = fcb[o];
            const float* wrow = &fcw[(size_t)o * 1024];
            #pragma unroll 4
            for (int j = 0; j < Hn; ++j) sum += hstage[0][j] * wrow[j];
            #pragma unroll 4
            for (int j = 0; j < Hn; ++j) sum += hstage[1][j] * wrow[512 + j];
            out[(size_t)b * On + o] = sum;
        }
    }
}

extern "C" void kernel_launch(void* const* d_in, const int* in_sizes, int n_in,
                              void* d_out, int out_size, void* d_ws, size_t ws_size,
                              hipStream_t stream)
{
    const float* x     = (const float*)d_in[0];
    const float* wih0f = (const float*)d_in[1];
    const float* whh0f = (const float*)d_in[2];
    const float* bih0f = (const float*)d_in[3];
    const float* bhh0f = (const float*)d_in[4];
    const float* wih0b = (const float*)d_in[5];
    const float* whh0b = (const float*)d_in[6];
    const float* bih0b = (const float*)d_in[7];
    const float* bhh0b = (const float*)d_in[8];
    const float* wih1f = (const float*)d_in[9];
    const float* whh1f = (const float*)d_in[10];
    const float* bih1f = (const float*)d_in[11];
    const float* bhh1f = (const float*)d_in[12];
    const float* wih1b = (const float*)d_in[13];
    const float* whh1b = (const float*)d_in[14];
    const float* bih1b = (const float*)d_in[15];
    const float* bhh1b = (const float*)d_in[16];
    const float* fcw   = (const float*)d_in[17];
    const float* fcb   = (const float*)d_in[18];

    char* ws = (char*)d_ws;
    size_t off = 0;
    unsigned* flags  = (unsigned*)(ws + off); off += (size_t)768 * 4;     // P1/P2/P3 packed
    unsigned* h0_pk  = (unsigned*)(ws + off); off += (size_t)2 * 2 * Bn * Hn * 4;
    unsigned* h1_pk  = (unsigned*)(ws + off); off += (size_t)2 * Bn * Hn * 4;
    size_t zero_end = off;                    // flags + recurrent h state must start zeroed
    unsigned* h1b_pk = (unsigned*)(ws + off); off += (size_t)Bn * Hn * 4;
    unsigned* out0_pk = (unsigned*)(ws + off); off += (size_t)Bn * Sn * 2 * Hn * 4;

    hipMemsetAsync(d_ws, 0, zero_end, stream);

    hipLaunchKernelGGL(bilstm_persistent, dim3(256), dim3(256), 0, stream,
        x, wih0f, whh0f, bih0f, bhh0f, wih0b, whh0b, bih0b, bhh0b,
        wih1f, whh1f, bih1f, bhh1f, wih1b, whh1b, bih1b, bhh1b,
        fcw, fcb,
        flags, h0_pk, h1_pk, h1b_pk, out0_pk,
        (float*)d_out);
}